// Round 1
// baseline (1185.979 us; speedup 1.0000x reference)
//
#include <hip/hip_runtime.h>
#include <math.h>

constexpr int Nn  = 65536;    // nodes
constexpr int Ne  = 1048576;  // edges
constexpr int Bg  = 256;      // graphs
constexpr int DIN = 32;
constexpr int D   = 64;

__device__ __forceinline__ float sigf(float x) { return 1.0f / (1.0f + expf(-x)); }

// ---------------------------------------------------------------------------
// Generic tiled GEMM:  C[N,G] = A[N,K] @ W[G,K]^T + b
// block = 256 threads, tile = 128 nodes x G gates, K staged in 32-chunks.
// thread tile = 8 nodes x TG gates (TG in {4,12}).
// ---------------------------------------------------------------------------
template <int K, int G, int TG>
__global__ __launch_bounds__(256, 2) void k_gemm(const float* __restrict__ A,
                                                 const float* __restrict__ W,
                                                 const float* __restrict__ b,
                                                 float* __restrict__ C) {
  constexpr int KC = 32;
  __shared__ float At[KC * 128];  // [k][node]
  __shared__ float Wt[KC * G];    // [k][gate]
  const int n0 = blockIdx.x * 128;
  const int tg = threadIdx.x & 15;   // 16 gate groups  (G = 16*TG)
  const int ng = threadIdx.x >> 4;   // 16 node groups  (128 = 16*8)

  float acc[8][TG];
#pragma unroll
  for (int j = 0; j < TG; ++j) {
    float bj = b[tg * TG + j];
#pragma unroll
    for (int i = 0; i < 8; ++i) acc[i][j] = bj;
  }

  for (int kc = 0; kc < K; kc += KC) {
    __syncthreads();  // protect LDS reuse across chunks
    for (int idx = threadIdx.x; idx < 128 * KC; idx += 256) {
      int r = idx >> 5, k = idx & 31;
      At[k * 128 + r] = A[(size_t)(n0 + r) * K + kc + k];
    }
    for (int idx = threadIdx.x; idx < G * KC; idx += 256) {
      int g = idx >> 5, k = idx & 31;
      Wt[k * G + g] = W[g * K + kc + k];
    }
    __syncthreads();
#pragma unroll
    for (int k = 0; k < KC; ++k) {
      float4 a0 = *(const float4*)&At[k * 128 + ng * 8];
      float4 a1 = *(const float4*)&At[k * 128 + ng * 8 + 4];
      float a[8] = {a0.x, a0.y, a0.z, a0.w, a1.x, a1.y, a1.z, a1.w};
      float w[TG];
#pragma unroll
      for (int j = 0; j < TG; j += 4) {
        float4 wv = *(const float4*)&Wt[k * G + tg * TG + j];
        w[j] = wv.x; w[j + 1] = wv.y; w[j + 2] = wv.z; w[j + 3] = wv.w;
      }
#pragma unroll
      for (int i = 0; i < 8; ++i)
#pragma unroll
        for (int j = 0; j < TG; ++j) acc[i][j] = fmaf(a[i], w[j], acc[i][j]);
    }
  }

  for (int i = 0; i < 8; ++i) {
    size_t base = (size_t)(n0 + ng * 8 + i) * G + tg * TG;
#pragma unroll
    for (int j = 0; j < TG; j += 4) {
      float4 v = {acc[i][j], acc[i][j + 1], acc[i][j + 2], acc[i][j + 3]};
      *(float4*)&C[base + j] = v;
    }
  }
}

// ---------------------------------------------------------------------------
// CSR build: histogram over dst, 1-block scan, placement
// ---------------------------------------------------------------------------
__global__ void k_hist(const int* __restrict__ eidx, int* __restrict__ count) {
  int t = blockIdx.x * 256 + threadIdx.x;
  if (t < Ne) atomicAdd(&count[eidx[Ne + t]], 1);
}

__global__ __launch_bounds__(1024) void k_scan(const int* __restrict__ count,
                                               int* __restrict__ rp,
                                               int* __restrict__ cursor) {
  __shared__ int sh[1024];
  int t = threadIdx.x;
  int base = t * 64;
  int sum = 0;
  for (int i = 0; i < 64; ++i) sum += count[base + i];
  sh[t] = sum;
  __syncthreads();
  for (int off = 1; off < 1024; off <<= 1) {
    int v = (t >= off) ? sh[t - off] : 0;
    __syncthreads();
    sh[t] += v;
    __syncthreads();
  }
  int run = (t == 0) ? 0 : sh[t - 1];
  for (int i = 0; i < 64; ++i) {
    int c = count[base + i];
    rp[base + i] = run;
    cursor[base + i] = run;
    run += c;
  }
  if (t == 1023) rp[Nn] = run;
}

__global__ void k_place(const int* __restrict__ eidx, int* __restrict__ cursor,
                        int* __restrict__ srcs) {
  int t = blockIdx.x * 256 + threadIdx.x;
  if (t < Ne) {
    int d = eidx[Ne + t];
    int p = atomicAdd(&cursor[d], 1);
    srcs[p] = eidx[t];
  }
}

// graph_ptr[g] = lower_bound(batch, g); batch is sorted
__global__ void k_graphptr(const int* __restrict__ batch, int* __restrict__ gp) {
  int g = threadIdx.x;
  if (g > Bg) return;
  int lo = 0, hi = Nn;
  while (lo < hi) {
    int mid = (lo + hi) >> 1;
    if (batch[mid] < g) lo = mid + 1; else hi = mid;
  }
  gp[g] = lo;
}

// ---------------------------------------------------------------------------
// transpose small weights once per launch (LSTM + W1)
// ---------------------------------------------------------------------------
__global__ void k_transpose(const float* __restrict__ W_ih,
                            const float* __restrict__ W_hh,
                            const float* __restrict__ W1,
                            float* __restrict__ WihT,   // [128][256]
                            float* __restrict__ WhhT,   // [64][256]
                            float* __restrict__ W1T) {  // [128][64]
  int idx = blockIdx.x * 256 + threadIdx.x;
  if (idx < 32768) {                 // W_ih [256][128]
    int row = idx / 128, k = idx % 128;
    WihT[k * 256 + row] = W_ih[idx];
  } else if (idx < 49152) {          // W_hh [256][64]
    int j = idx - 32768;
    int row = j / 64, k = j % 64;
    WhhT[k * 256 + row] = W_hh[j];
  } else if (idx < 57344) {          // W1 [64][128]
    int j = idx - 49152;
    int row = j / 128, k = j % 128;
    W1T[k * 64 + row] = W1[j];
  }
}

// fill x-columns of inp96 (cols 64..95), once per launch
__global__ void k_fillx(const float* __restrict__ x, float* __restrict__ inp96) {
  int idx = blockIdx.x * 256 + threadIdx.x;
  if (idx < Nn * DIN) {
    int n = idx / DIN, c = idx % DIN;
    inp96[(size_t)n * 96 + D + c] = x[idx];
  }
}

// ---------------------------------------------------------------------------
// CSR aggregate: inp96[n][0:64] = sum over in-edges of lin[src]
// 16 threads per node, float4 per thread
// ---------------------------------------------------------------------------
__global__ void k_aggregate(const int* __restrict__ rp, const int* __restrict__ srcs,
                            const float* __restrict__ lin, float* __restrict__ inp96) {
  int t = blockIdx.x * 256 + threadIdx.x;
  int n = t >> 4;
  int q = t & 15;
  int s = rp[n], e = rp[n + 1];
  float4 acc = {0.f, 0.f, 0.f, 0.f};
  for (int i = s; i < e; ++i) {
    int src = srcs[i];
    float4 v = *(const float4*)&lin[(size_t)src * 64 + q * 4];
    acc.x += v.x; acc.y += v.y; acc.z += v.z; acc.w += v.w;
  }
  *(float4*)&inp96[(size_t)n * 96 + q * 4] = acc;
}

// ---------------------------------------------------------------------------
// GRU combine: h' = (1-z)*tanh(gi_n + r*gh_n) + z*h
// ---------------------------------------------------------------------------
__global__ void k_combine(const float* __restrict__ gi, const float* __restrict__ gh,
                          const float* __restrict__ h, float* __restrict__ h2) {
  int idx = blockIdx.x * 256 + threadIdx.x;
  int n = idx >> 6, d = idx & 63;
  size_t b = (size_t)n * 192 + d;
  float gir = gi[b], giz = gi[b + 64], gin = gi[b + 128];
  float ghr = gh[b], ghz = gh[b + 64], ghn = gh[b + 128];
  float r = sigf(gir + ghr);
  float z = sigf(giz + ghz);
  float ng = tanhf(gin + r * ghn);
  h2[idx] = (1.f - z) * ng + z * h[idx];
}

// ---------------------------------------------------------------------------
// One Set2Set iteration: per-graph block (64 threads = 1 wave)
// LSTM cell -> attention softmax over the graph's nodes -> q_star update
// ---------------------------------------------------------------------------
__global__ __launch_bounds__(64) void k_s2s(float* __restrict__ q_star,
                                            float* __restrict__ hl, float* __restrict__ cl,
                                            const float* __restrict__ out,
                                            const int* __restrict__ gp,
                                            float* __restrict__ e_buf,
                                            const float* __restrict__ WihT,
                                            const float* __restrict__ WhhT,
                                            const float* __restrict__ b_ih,
                                            const float* __restrict__ b_hh) {
  int g = blockIdx.x;
  int lane = threadIdx.x;
  __shared__ float qs[128];
  __shared__ float hsh[64];
  float hld = hl[g * 64 + lane];
  float cld = cl[g * 64 + lane];
  qs[lane] = q_star[g * 128 + lane];
  qs[64 + lane] = q_star[g * 128 + 64 + lane];
  hsh[lane] = hld;
  __syncthreads();

  // LSTM gates: rows lane, 64+lane, 128+lane, 192+lane (i,f,g,o)
  float acc[4];
#pragma unroll
  for (int j = 0; j < 4; ++j) acc[j] = b_ih[j * 64 + lane] + b_hh[j * 64 + lane];
  for (int k = 0; k < 128; ++k) {
    float v = qs[k];
#pragma unroll
    for (int j = 0; j < 4; ++j) acc[j] = fmaf(WihT[k * 256 + j * 64 + lane], v, acc[j]);
  }
  for (int k = 0; k < 64; ++k) {
    float v = hsh[k];
#pragma unroll
    for (int j = 0; j < 4; ++j) acc[j] = fmaf(WhhT[k * 256 + j * 64 + lane], v, acc[j]);
  }
  float ig = sigf(acc[0]), fg = sigf(acc[1]);
  float gg = tanhf(acc[2]), og = sigf(acc[3]);
  cld = fg * cld + ig * gg;
  hld = og * tanhf(cld);  // q[lane]

  int s = gp[g], e = gp[g + 1];
  // pass 1: e_i = out[i] . q ; track max
  float emax = -INFINITY;
  for (int i = s; i < e; ++i) {
    float p = out[(size_t)i * 64 + lane] * hld;
#pragma unroll
    for (int o = 32; o >= 1; o >>= 1) p += __shfl_xor(p, o);
    if (lane == 0) e_buf[i] = p;
    emax = fmaxf(emax, p);
  }
  // pass 2: softmax-weighted feature sum
  float accr = 0.f, asum = 0.f;
  for (int i = s; i < e; ++i) {
    float a = expf(e_buf[i] - emax);
    asum += a;
    accr = fmaf(a, out[(size_t)i * 64 + lane], accr);
  }
  float r = (e > s) ? accr / fmaxf(asum, 1e-16f) : 0.f;

  hl[g * 64 + lane] = hld;
  cl[g * 64 + lane] = cld;
  q_star[g * 128 + lane] = hld;
  q_star[g * 128 + 64 + lane] = r;
}

// ---------------------------------------------------------------------------
// Head: hid = relu(q_star @ W1^T + b1); logits = hid @ W2^T + b2; log_softmax
// ---------------------------------------------------------------------------
__global__ __launch_bounds__(64) void k_head(const float* __restrict__ q_star,
                                             const float* __restrict__ W1T,
                                             const float* __restrict__ b1,
                                             const float* __restrict__ W2,
                                             const float* __restrict__ b2,
                                             float* __restrict__ outp) {
  int g = blockIdx.x;
  int lane = threadIdx.x;
  __shared__ float qsh[128];
  __shared__ float hsh[64];
  __shared__ float l4[4];
  qsh[lane] = q_star[g * 128 + lane];
  qsh[64 + lane] = q_star[g * 128 + 64 + lane];
  __syncthreads();
  float acc = b1[lane];
  for (int k = 0; k < 128; ++k) acc = fmaf(W1T[k * 64 + lane], qsh[k], acc);
  hsh[lane] = fmaxf(acc, 0.f);
  __syncthreads();
  if (lane < 4) {
    float lg = b2[lane];
    for (int d = 0; d < 64; ++d) lg = fmaf(W2[lane * 64 + d], hsh[d], lg);
    l4[lane] = lg;
  }
  __syncthreads();
  if (lane < 4) {
    float m = fmaxf(fmaxf(l4[0], l4[1]), fmaxf(l4[2], l4[3]));
    float ssum = expf(l4[0] - m) + expf(l4[1] - m) + expf(l4[2] - m) + expf(l4[3] - m);
    outp[g * 4 + lane] = l4[lane] - m - logf(ssum);
  }
}

// ---------------------------------------------------------------------------
extern "C" void kernel_launch(void* const* d_in, const int* in_sizes, int n_in,
                              void* d_out, int out_size, void* d_ws, size_t ws_size,
                              hipStream_t stream) {
  const float* x        = (const float*)d_in[0];
  const int*   eidx     = (const int*)d_in[1];
  const int*   batch    = (const int*)d_in[2];
  const float* W_mlp    = (const float*)d_in[3];
  const float* b_mlp    = (const float*)d_in[4];
  const float* W_conv   = (const float*)d_in[5];
  const float* b_conv   = (const float*)d_in[6];
  const float* gW_ih    = (const float*)d_in[7];
  const float* gW_hh    = (const float*)d_in[8];
  const float* gb_ih    = (const float*)d_in[9];
  const float* gb_hh    = (const float*)d_in[10];
  const float* lW_ih    = (const float*)d_in[11];
  const float* lW_hh    = (const float*)d_in[12];
  const float* lb_ih    = (const float*)d_in[13];
  const float* lb_hh    = (const float*)d_in[14];
  const float* W1       = (const float*)d_in[15];
  const float* b1       = (const float*)d_in[16];
  const float* W2       = (const float*)d_in[17];
  const float* b2       = (const float*)d_in[18];
  float* outp = (float*)d_out;

  // ---- workspace layout ----
  char* ws = (char*)d_ws;
  size_t off = 0;
  auto alloc = [&](size_t bytes) { size_t r = off; off = (off + bytes + 255) & ~(size_t)255; return r; };
  float* outA  = (float*)(ws + alloc((size_t)Nn * 64 * 4));
  float* outB  = (float*)(ws + alloc((size_t)Nn * 64 * 4));
  float* inp96 = (float*)(ws + alloc((size_t)Nn * 96 * 4));
  float* gi    = (float*)(ws + alloc((size_t)Nn * 192 * 4));
  float* ghbuf = (float*)(ws + alloc((size_t)Nn * 192 * 4));  // lin aliases its head
  float* lin   = ghbuf;
  int*   count = (int*)(ws + alloc((size_t)Nn * 4));
  int*   rp    = (int*)(ws + alloc((size_t)(Nn + 1) * 4));
  int*   cursor= (int*)(ws + alloc((size_t)Nn * 4));
  int*   srcs  = (int*)(ws + alloc((size_t)Ne * 4));
  int*   gp    = (int*)(ws + alloc((size_t)(Bg + 1) * 4));
  float* e_buf = (float*)(ws + alloc((size_t)Nn * 4));
  float* WihT  = (float*)(ws + alloc((size_t)128 * 256 * 4));
  float* WhhT  = (float*)(ws + alloc((size_t)64 * 256 * 4));
  float* W1T   = (float*)(ws + alloc((size_t)128 * 64 * 4));
  float* s2s   = (float*)(ws + alloc((size_t)Bg * (128 + 64 + 64) * 4));  // q_star|hl|cl
  float* q_star = s2s;
  float* hl     = s2s + Bg * 128;
  float* cl     = s2s + Bg * 128 + Bg * 64;
  (void)in_sizes; (void)n_in; (void)out_size; (void)ws_size;

  // zero counters + set2set state
  hipMemsetAsync(count, 0, (size_t)Nn * 4, stream);
  hipMemsetAsync(s2s, 0, (size_t)Bg * 256 * 4, stream);

  // CSR build + small transposes + graph_ptr
  k_hist<<<Ne / 256, 256, 0, stream>>>(eidx, count);
  k_scan<<<1, 1024, 0, stream>>>(count, rp, cursor);
  k_place<<<Ne / 256, 256, 0, stream>>>(eidx, cursor, srcs);
  k_graphptr<<<1, 512, 0, stream>>>(batch, gp);
  k_transpose<<<224, 256, 0, stream>>>(lW_ih, lW_hh, W1, WihT, WhhT, W1T);

  // conv1: out = x @ W_mlp^T + b_mlp
  k_gemm<32, 64, 4><<<Nn / 128, 256, 0, stream>>>(x, W_mlp, b_mlp, outA);
  k_fillx<<<Nn * DIN / 256, 256, 0, stream>>>(x, inp96);

  float* h  = outA;
  float* h2 = outB;
  for (int step = 0; step < 2; ++step) {
    k_gemm<64, 64, 4><<<Nn / 128, 256, 0, stream>>>(h, W_conv, b_conv, lin);
    k_aggregate<<<Nn * 16 / 256, 256, 0, stream>>>(rp, srcs, lin, inp96);
    k_gemm<64, 192, 12><<<Nn / 128, 256, 0, stream>>>(h, gW_hh, gb_hh, ghbuf);
    k_gemm<96, 192, 12><<<Nn / 128, 256, 0, stream>>>(inp96, gW_ih, gb_ih, gi);
    k_combine<<<Nn * 64 / 256, 256, 0, stream>>>(gi, ghbuf, h, h2);
    float* tmp = h; h = h2; h2 = tmp;
  }
  // h now points to final node features (outA after 2 steps)

  for (int it = 0; it < 3; ++it) {
    k_s2s<<<Bg, 64, 0, stream>>>(q_star, hl, cl, h, gp, e_buf, WihT, WhhT, lb_ih, lb_hh);
  }
  k_head<<<Bg, 64, 0, stream>>>(q_star, W1T, b1, W2, b2, outp);
}

// Round 2
// 1109.038 us; speedup vs baseline: 1.0694x; 1.0694x over previous
//
#include <hip/hip_runtime.h>
#include <math.h>

constexpr int Nn  = 65536;    // nodes
constexpr int Ne  = 1048576;  // edges
constexpr int Bg  = 256;      // graphs
constexpr int DIN = 32;
constexpr int D   = 64;

__device__ __forceinline__ float sigf(float x) { return 1.0f / (1.0f + expf(-x)); }

// monotone float<->unsigned key for atomicMax over floats
__device__ __forceinline__ unsigned fkey(float f) {
  unsigned b = __float_as_uint(f);
  return (b & 0x80000000u) ? ~b : (b | 0x80000000u);
}
__device__ __forceinline__ float fkey_inv(unsigned u) {
  unsigned b = (u & 0x80000000u) ? (u & 0x7FFFFFFFu) : ~u;
  return __uint_as_float(b);
}

// ---------------------------------------------------------------------------
// Generic tiled GEMM:  C[N,G] = A[N,K] @ W[G,K]^T + b
// block = 256 threads, tile = 128 nodes x G gates, K staged in 32-chunks.
// ---------------------------------------------------------------------------
template <int K, int G, int TG>
__global__ __launch_bounds__(256, 2) void k_gemm(const float* __restrict__ A,
                                                 const float* __restrict__ W,
                                                 const float* __restrict__ b,
                                                 float* __restrict__ C) {
  constexpr int KC = 32;
  __shared__ float At[KC * 128];  // [k][node]
  __shared__ float Wt[KC * G];    // [k][gate]
  const int n0 = blockIdx.x * 128;
  const int tg = threadIdx.x & 15;   // 16 gate groups  (G = 16*TG)
  const int ng = threadIdx.x >> 4;   // 16 node groups  (128 = 16*8)

  float acc[8][TG];
#pragma unroll
  for (int j = 0; j < TG; ++j) {
    float bj = b[tg * TG + j];
#pragma unroll
    for (int i = 0; i < 8; ++i) acc[i][j] = bj;
  }

  for (int kc = 0; kc < K; kc += KC) {
    __syncthreads();
    for (int idx = threadIdx.x; idx < 128 * KC; idx += 256) {
      int r = idx >> 5, k = idx & 31;
      At[k * 128 + r] = A[(size_t)(n0 + r) * K + kc + k];
    }
    for (int idx = threadIdx.x; idx < G * KC; idx += 256) {
      int g = idx >> 5, k = idx & 31;
      Wt[k * G + g] = W[g * K + kc + k];
    }
    __syncthreads();
#pragma unroll
    for (int k = 0; k < KC; ++k) {
      float4 a0 = *(const float4*)&At[k * 128 + ng * 8];
      float4 a1 = *(const float4*)&At[k * 128 + ng * 8 + 4];
      float a[8] = {a0.x, a0.y, a0.z, a0.w, a1.x, a1.y, a1.z, a1.w};
      float w[TG];
#pragma unroll
      for (int j = 0; j < TG; j += 4) {
        float4 wv = *(const float4*)&Wt[k * G + tg * TG + j];
        w[j] = wv.x; w[j + 1] = wv.y; w[j + 2] = wv.z; w[j + 3] = wv.w;
      }
#pragma unroll
      for (int i = 0; i < 8; ++i)
#pragma unroll
        for (int j = 0; j < TG; ++j) acc[i][j] = fmaf(a[i], w[j], acc[i][j]);
    }
  }

  for (int i = 0; i < 8; ++i) {
    size_t base = (size_t)(n0 + ng * 8 + i) * G + tg * TG;
#pragma unroll
    for (int j = 0; j < TG; j += 4) {
      float4 v = {acc[i][j], acc[i][j + 1], acc[i][j + 2], acc[i][j + 3]};
      *(float4*)&C[base + j] = v;
    }
  }
}

// ---------------------------------------------------------------------------
// CSR build: histogram over dst, 1-block scan, placement
// ---------------------------------------------------------------------------
__global__ void k_hist(const int* __restrict__ eidx, int* __restrict__ count) {
  int t = blockIdx.x * 256 + threadIdx.x;
  if (t < Ne) atomicAdd(&count[eidx[Ne + t]], 1);
}

__global__ __launch_bounds__(1024) void k_scan(const int* __restrict__ count,
                                               int* __restrict__ rp,
                                               int* __restrict__ cursor) {
  __shared__ int sh[1024];
  int t = threadIdx.x;
  int base = t * 64;
  int sum = 0;
  for (int i = 0; i < 64; ++i) sum += count[base + i];
  sh[t] = sum;
  __syncthreads();
  for (int off = 1; off < 1024; off <<= 1) {
    int v = (t >= off) ? sh[t - off] : 0;
    __syncthreads();
    sh[t] += v;
    __syncthreads();
  }
  int run = (t == 0) ? 0 : sh[t - 1];
  for (int i = 0; i < 64; ++i) {
    int c = count[base + i];
    rp[base + i] = run;
    cursor[base + i] = run;
    run += c;
  }
  if (t == 1023) rp[Nn] = run;
}

__global__ void k_place(const int* __restrict__ eidx, int* __restrict__ cursor,
                        int* __restrict__ srcs) {
  int t = blockIdx.x * 256 + threadIdx.x;
  if (t < Ne) {
    int d = eidx[Ne + t];
    int p = atomicAdd(&cursor[d], 1);
    srcs[p] = eidx[t];
  }
}

// graph_ptr[g] = lower_bound(batch, g); batch is sorted
__global__ void k_graphptr(const int* __restrict__ batch, int* __restrict__ gp) {
  int g = threadIdx.x;
  if (g > Bg) return;
  int lo = 0, hi = Nn;
  while (lo < hi) {
    int mid = (lo + hi) >> 1;
    if (batch[mid] < g) lo = mid + 1; else hi = mid;
  }
  gp[g] = lo;
}

// ---------------------------------------------------------------------------
// transpose small weights once per launch (LSTM + W1)
// ---------------------------------------------------------------------------
__global__ void k_transpose(const float* __restrict__ W_ih,
                            const float* __restrict__ W_hh,
                            const float* __restrict__ W1,
                            float* __restrict__ WihT,   // [128][256]
                            float* __restrict__ WhhT,   // [64][256]
                            float* __restrict__ W1T) {  // [128][64]
  int idx = blockIdx.x * 256 + threadIdx.x;
  if (idx < 32768) {                 // W_ih [256][128]
    int row = idx / 128, k = idx % 128;
    WihT[k * 256 + row] = W_ih[idx];
  } else if (idx < 49152) {          // W_hh [256][64]
    int j = idx - 32768;
    int row = j / 64, k = j % 64;
    WhhT[k * 256 + row] = W_hh[j];
  } else if (idx < 57344) {          // W1 [64][128]
    int j = idx - 49152;
    int row = j / 128, k = j % 128;
    W1T[k * 64 + row] = W1[j];
  }
}

// fill x-columns of inp96 (cols 64..95), once per launch
__global__ void k_fillx(const float* __restrict__ x, float* __restrict__ inp96) {
  int idx = blockIdx.x * 256 + threadIdx.x;
  if (idx < Nn * DIN) {
    int n = idx / DIN, c = idx % DIN;
    inp96[(size_t)n * 96 + D + c] = x[idx];
  }
}

// ---------------------------------------------------------------------------
// CSR aggregate: inp96[n][0:64] = sum over in-edges of lin[src]
// ---------------------------------------------------------------------------
__global__ void k_aggregate(const int* __restrict__ rp, const int* __restrict__ srcs,
                            const float* __restrict__ lin, float* __restrict__ inp96) {
  int t = blockIdx.x * 256 + threadIdx.x;
  int n = t >> 4;
  int q = t & 15;
  int s = rp[n], e = rp[n + 1];
  float4 acc = {0.f, 0.f, 0.f, 0.f};
  for (int i = s; i < e; ++i) {
    int src = srcs[i];
    float4 v = *(const float4*)&lin[(size_t)src * 64 + q * 4];
    acc.x += v.x; acc.y += v.y; acc.z += v.z; acc.w += v.w;
  }
  *(float4*)&inp96[(size_t)n * 96 + q * 4] = acc;
}

// ---------------------------------------------------------------------------
// GRU combine: h' = (1-z)*tanh(gi_n + r*gh_n) + z*h
// ---------------------------------------------------------------------------
__global__ void k_combine(const float* __restrict__ gi, const float* __restrict__ gh,
                          const float* __restrict__ h, float* __restrict__ h2) {
  int idx = blockIdx.x * 256 + threadIdx.x;
  int n = idx >> 6, d = idx & 63;
  size_t b = (size_t)n * 192 + d;
  float gir = gi[b], giz = gi[b + 64], gin = gi[b + 128];
  float ghr = gh[b], ghz = gh[b + 64], ghn = gh[b + 128];
  float r = sigf(gir + ghr);
  float z = sigf(giz + ghz);
  float ng = tanhf(gin + r * ghn);
  h2[idx] = (1.f - z) * ng + z * h[idx];
}

// ---------------------------------------------------------------------------
// Set2Set phase 1: LSTM cell. One block per graph, one thread per gate row.
// Writes q into q_star[:,0:64], re-arms emax key.
// ---------------------------------------------------------------------------
__global__ __launch_bounds__(256) void k_lstm(float* __restrict__ q_star,
                                              float* __restrict__ hl,
                                              float* __restrict__ cl,
                                              const float* __restrict__ WihT,
                                              const float* __restrict__ WhhT,
                                              const float* __restrict__ b_ih,
                                              const float* __restrict__ b_hh,
                                              unsigned* __restrict__ emax_u) {
  int g = blockIdx.x, t = threadIdx.x;
  __shared__ float qs[128], hsh[64], gates[256];
  if (t < 128) qs[t] = q_star[g * 128 + t];
  else if (t < 192) hsh[t - 128] = hl[g * 64 + (t - 128)];
  if (t == 0) emax_u[g] = 0x007FFFFFu;  // fkey(-inf)
  __syncthreads();
  float acc = b_ih[t] + b_hh[t];
  for (int k = 0; k < 128; ++k) acc = fmaf(WihT[k * 256 + t], qs[k], acc);
  for (int k = 0; k < 64; ++k)  acc = fmaf(WhhT[k * 256 + t], hsh[k], acc);
  gates[t] = acc;
  __syncthreads();
  if (t < 64) {
    float ig = sigf(gates[t]),       fg = sigf(gates[64 + t]);
    float gg = tanhf(gates[128 + t]), og = sigf(gates[192 + t]);
    float c = fg * cl[g * 64 + t] + ig * gg;
    float q = og * tanhf(c);
    cl[g * 64 + t] = c;
    hl[g * 64 + t] = q;
    q_star[g * 128 + t] = q;
  }
}

// ---------------------------------------------------------------------------
// Set2Set phase 2: e[n] = out[n] . q[batch[n]] for all nodes; atomicMax emax.
// 16 threads per node, float4 per thread.
// ---------------------------------------------------------------------------
__global__ __launch_bounds__(256) void k_dot(const float* __restrict__ out,
                                             const float* __restrict__ q_star,
                                             const int* __restrict__ batch,
                                             float* __restrict__ e_buf,
                                             unsigned* __restrict__ emax_u) {
  int t = blockIdx.x * 256 + threadIdx.x;
  int n = t >> 4, q16 = t & 15;
  int g = batch[n];
  float4 o  = *(const float4*)&out[(size_t)n * 64 + q16 * 4];
  float4 qv = *(const float4*)&q_star[g * 128 + q16 * 4];
  float p = o.x * qv.x + o.y * qv.y + o.z * qv.z + o.w * qv.w;
  p += __shfl_xor(p, 1); p += __shfl_xor(p, 2);
  p += __shfl_xor(p, 4); p += __shfl_xor(p, 8);
  if (q16 == 0) {
    e_buf[n] = p;
    atomicMax(&emax_u[g], fkey(p));
  }
}

// ---------------------------------------------------------------------------
// Set2Set phase 3: softmax-weighted feature sum per graph.
// One block per graph, 4 waves, lane = feature dim, wave-strided nodes.
// ---------------------------------------------------------------------------
__global__ __launch_bounds__(256) void k_wsum(const float* __restrict__ out,
                                              const float* __restrict__ e_buf,
                                              const unsigned* __restrict__ emax_u,
                                              const int* __restrict__ gp,
                                              float* __restrict__ q_star) {
  int g = blockIdx.x;
  int t = threadIdx.x;
  int w = t >> 6, lane = t & 63;
  __shared__ float partial[4][64];
  __shared__ float asum_p[4];
  float emax = fkey_inv(emax_u[g]);
  if (!isfinite(emax)) emax = 0.f;
  int s = gp[g], e = gp[g + 1];
  float acc = 0.f, asum = 0.f;
  for (int i = s + w; i < e; i += 4) {
    float a = expf(e_buf[i] - emax);
    asum += a;
    acc = fmaf(a, out[(size_t)i * 64 + lane], acc);
  }
  partial[w][lane] = acc;
  if (lane == 0) asum_p[w] = asum;
  __syncthreads();
  if (t < 64) {
    float r  = partial[0][t] + partial[1][t] + partial[2][t] + partial[3][t];
    float as = asum_p[0] + asum_p[1] + asum_p[2] + asum_p[3];
    q_star[g * 128 + 64 + t] = (e > s) ? r / fmaxf(as, 1e-16f) : 0.f;
  }
}

// ---------------------------------------------------------------------------
// Head: hid = relu(q_star @ W1^T + b1); logits = hid @ W2^T + b2; log_softmax
// ---------------------------------------------------------------------------
__global__ __launch_bounds__(64) void k_head(const float* __restrict__ q_star,
                                             const float* __restrict__ W1T,
                                             const float* __restrict__ b1,
                                             const float* __restrict__ W2,
                                             const float* __restrict__ b2,
                                             float* __restrict__ outp) {
  int g = blockIdx.x;
  int lane = threadIdx.x;
  __shared__ float qsh[128];
  __shared__ float hsh[64];
  __shared__ float l4[4];
  qsh[lane] = q_star[g * 128 + lane];
  qsh[64 + lane] = q_star[g * 128 + 64 + lane];
  __syncthreads();
  float acc = b1[lane];
  for (int k = 0; k < 128; ++k) acc = fmaf(W1T[k * 64 + lane], qsh[k], acc);
  hsh[lane] = fmaxf(acc, 0.f);
  __syncthreads();
  if (lane < 4) {
    float lg = b2[lane];
    for (int d = 0; d < 64; ++d) lg = fmaf(W2[lane * 64 + d], hsh[d], lg);
    l4[lane] = lg;
  }
  __syncthreads();
  if (lane < 4) {
    float m = fmaxf(fmaxf(l4[0], l4[1]), fmaxf(l4[2], l4[3]));
    float ssum = expf(l4[0] - m) + expf(l4[1] - m) + expf(l4[2] - m) + expf(l4[3] - m);
    outp[g * 4 + lane] = l4[lane] - m - logf(ssum);
  }
}

// ---------------------------------------------------------------------------
extern "C" void kernel_launch(void* const* d_in, const int* in_sizes, int n_in,
                              void* d_out, int out_size, void* d_ws, size_t ws_size,
                              hipStream_t stream) {
  const float* x        = (const float*)d_in[0];
  const int*   eidx     = (const int*)d_in[1];
  const int*   batch    = (const int*)d_in[2];
  const float* W_mlp    = (const float*)d_in[3];
  const float* b_mlp    = (const float*)d_in[4];
  const float* W_conv   = (const float*)d_in[5];
  const float* b_conv   = (const float*)d_in[6];
  const float* gW_ih    = (const float*)d_in[7];
  const float* gW_hh    = (const float*)d_in[8];
  const float* gb_ih    = (const float*)d_in[9];
  const float* gb_hh    = (const float*)d_in[10];
  const float* lW_ih    = (const float*)d_in[11];
  const float* lW_hh    = (const float*)d_in[12];
  const float* lb_ih    = (const float*)d_in[13];
  const float* lb_hh    = (const float*)d_in[14];
  const float* W1       = (const float*)d_in[15];
  const float* b1       = (const float*)d_in[16];
  const float* W2       = (const float*)d_in[17];
  const float* b2       = (const float*)d_in[18];
  float* outp = (float*)d_out;

  // ---- workspace layout ----
  char* ws = (char*)d_ws;
  size_t off = 0;
  auto alloc = [&](size_t bytes) { size_t r = off; off = (off + bytes + 255) & ~(size_t)255; return r; };
  float* outA  = (float*)(ws + alloc((size_t)Nn * 64 * 4));
  float* outB  = (float*)(ws + alloc((size_t)Nn * 64 * 4));
  float* inp96 = (float*)(ws + alloc((size_t)Nn * 96 * 4));
  float* gi    = (float*)(ws + alloc((size_t)Nn * 192 * 4));
  float* ghbuf = (float*)(ws + alloc((size_t)Nn * 192 * 4));  // lin aliases its head
  float* lin   = ghbuf;
  int*   count = (int*)(ws + alloc((size_t)Nn * 4));
  int*   rp    = (int*)(ws + alloc((size_t)(Nn + 1) * 4));
  int*   cursor= (int*)(ws + alloc((size_t)Nn * 4));
  int*   srcs  = (int*)(ws + alloc((size_t)Ne * 4));
  int*   gp    = (int*)(ws + alloc((size_t)(Bg + 1) * 4));
  float* e_buf = (float*)(ws + alloc((size_t)Nn * 4));
  float* WihT  = (float*)(ws + alloc((size_t)128 * 256 * 4));
  float* WhhT  = (float*)(ws + alloc((size_t)64 * 256 * 4));
  float* W1T   = (float*)(ws + alloc((size_t)128 * 64 * 4));
  float* s2s   = (float*)(ws + alloc((size_t)Bg * (128 + 64 + 64) * 4));  // q_star|hl|cl
  unsigned* emax_u = (unsigned*)(ws + alloc((size_t)Bg * 4));
  float* q_star = s2s;
  float* hl     = s2s + Bg * 128;
  float* cl     = s2s + Bg * 128 + Bg * 64;
  (void)in_sizes; (void)n_in; (void)out_size; (void)ws_size;

  // zero counters + set2set state
  hipMemsetAsync(count, 0, (size_t)Nn * 4, stream);
  hipMemsetAsync(s2s, 0, (size_t)Bg * 256 * 4, stream);

  // CSR build + small transposes + graph_ptr
  k_hist<<<Ne / 256, 256, 0, stream>>>(eidx, count);
  k_scan<<<1, 1024, 0, stream>>>(count, rp, cursor);
  k_place<<<Ne / 256, 256, 0, stream>>>(eidx, cursor, srcs);
  k_graphptr<<<1, 512, 0, stream>>>(batch, gp);
  k_transpose<<<224, 256, 0, stream>>>(lW_ih, lW_hh, W1, WihT, WhhT, W1T);

  // conv1: out = x @ W_mlp^T + b_mlp
  k_gemm<32, 64, 4><<<Nn / 128, 256, 0, stream>>>(x, W_mlp, b_mlp, outA);
  k_fillx<<<Nn * DIN / 256, 256, 0, stream>>>(x, inp96);

  float* h  = outA;
  float* h2 = outB;
  for (int step = 0; step < 2; ++step) {
    k_gemm<64, 64, 4><<<Nn / 128, 256, 0, stream>>>(h, W_conv, b_conv, lin);
    k_aggregate<<<Nn * 16 / 256, 256, 0, stream>>>(rp, srcs, lin, inp96);
    k_gemm<64, 192, 12><<<Nn / 128, 256, 0, stream>>>(h, gW_hh, gb_hh, ghbuf);
    k_gemm<96, 192, 12><<<Nn / 128, 256, 0, stream>>>(inp96, gW_ih, gb_ih, gi);
    k_combine<<<Nn * 64 / 256, 256, 0, stream>>>(gi, ghbuf, h, h2);
    float* tmp = h; h = h2; h2 = tmp;
  }
  // h now points to final node features

  for (int it = 0; it < 3; ++it) {
    k_lstm<<<Bg, 256, 0, stream>>>(q_star, hl, cl, WihT, WhhT, lb_ih, lb_hh, emax_u);
    k_dot<<<Nn * 16 / 256, 256, 0, stream>>>(h, q_star, batch, e_buf, emax_u);
    k_wsum<<<Bg, 256, 0, stream>>>(h, e_buf, emax_u, gp, q_star);
  }
  k_head<<<Bg, 64, 0, stream>>>(q_star, W1T, b1, W2, b2, outp);
}

// Round 3
// 755.732 us; speedup vs baseline: 1.5693x; 1.4675x over previous
//
#include <hip/hip_runtime.h>
#include <math.h>

constexpr int Nn  = 65536;    // nodes
constexpr int Ne  = 1048576;  // edges
constexpr int Bg  = 256;      // graphs
constexpr int DIN = 32;
constexpr int D   = 64;

__device__ __forceinline__ float sigf(float x) { return 1.0f / (1.0f + expf(-x)); }

// ---------------------------------------------------------------------------
// Generic tiled GEMM:  C[N,G] = A[N,K] @ W[G,K]^T + b
// block = 256 threads, tile = 128 nodes x G gates, K staged in 32-chunks.
// ---------------------------------------------------------------------------
template <int K, int G, int TG>
__global__ __launch_bounds__(256, 2) void k_gemm(const float* __restrict__ A,
                                                 const float* __restrict__ W,
                                                 const float* __restrict__ b,
                                                 float* __restrict__ C) {
  constexpr int KC = 32;
  __shared__ float At[KC * 128];  // [k][node]
  __shared__ float Wt[KC * G];    // [k][gate]
  const int n0 = blockIdx.x * 128;
  const int tg = threadIdx.x & 15;   // 16 gate groups  (G = 16*TG)
  const int ng = threadIdx.x >> 4;   // 16 node groups  (128 = 16*8)

  float acc[8][TG];
#pragma unroll
  for (int j = 0; j < TG; ++j) {
    float bj = b[tg * TG + j];
#pragma unroll
    for (int i = 0; i < 8; ++i) acc[i][j] = bj;
  }

  for (int kc = 0; kc < K; kc += KC) {
    __syncthreads();
    for (int idx = threadIdx.x; idx < 128 * KC; idx += 256) {
      int r = idx >> 5, k = idx & 31;
      At[k * 128 + r] = A[(size_t)(n0 + r) * K + kc + k];
    }
    for (int idx = threadIdx.x; idx < G * KC; idx += 256) {
      int g = idx >> 5, k = idx & 31;
      Wt[k * G + g] = W[g * K + kc + k];
    }
    __syncthreads();
#pragma unroll
    for (int k = 0; k < KC; ++k) {
      float4 a0 = *(const float4*)&At[k * 128 + ng * 8];
      float4 a1 = *(const float4*)&At[k * 128 + ng * 8 + 4];
      float a[8] = {a0.x, a0.y, a0.z, a0.w, a1.x, a1.y, a1.z, a1.w};
      float w[TG];
#pragma unroll
      for (int j = 0; j < TG; j += 4) {
        float4 wv = *(const float4*)&Wt[k * G + tg * TG + j];
        w[j] = wv.x; w[j + 1] = wv.y; w[j + 2] = wv.z; w[j + 3] = wv.w;
      }
#pragma unroll
      for (int i = 0; i < 8; ++i)
#pragma unroll
        for (int j = 0; j < TG; ++j) acc[i][j] = fmaf(a[i], w[j], acc[i][j]);
    }
  }

  for (int i = 0; i < 8; ++i) {
    size_t base = (size_t)(n0 + ng * 8 + i) * G + tg * TG;
#pragma unroll
    for (int j = 0; j < TG; j += 4) {
      float4 v = {acc[i][j], acc[i][j + 1], acc[i][j + 2], acc[i][j + 3]};
      *(float4*)&C[base + j] = v;
    }
  }
}

// ---------------------------------------------------------------------------
// CSR build: histogram over dst, 1-block scan, placement
// ---------------------------------------------------------------------------
__global__ void k_hist(const int* __restrict__ eidx, int* __restrict__ count) {
  int t = blockIdx.x * 256 + threadIdx.x;
  if (t < Ne) atomicAdd(&count[eidx[Ne + t]], 1);
}

__global__ __launch_bounds__(1024) void k_scan(const int* __restrict__ count,
                                               int* __restrict__ rp,
                                               int* __restrict__ cursor) {
  __shared__ int sh[1024];
  int t = threadIdx.x;
  int base = t * 64;
  int sum = 0;
  for (int i = 0; i < 64; ++i) sum += count[base + i];
  sh[t] = sum;
  __syncthreads();
  for (int off = 1; off < 1024; off <<= 1) {
    int v = (t >= off) ? sh[t - off] : 0;
    __syncthreads();
    sh[t] += v;
    __syncthreads();
  }
  int run = (t == 0) ? 0 : sh[t - 1];
  for (int i = 0; i < 64; ++i) {
    int c = count[base + i];
    rp[base + i] = run;
    cursor[base + i] = run;
    run += c;
  }
  if (t == 1023) rp[Nn] = run;
}

__global__ void k_place(const int* __restrict__ eidx, int* __restrict__ cursor,
                        int* __restrict__ srcs) {
  int t = blockIdx.x * 256 + threadIdx.x;
  if (t < Ne) {
    int d = eidx[Ne + t];
    int p = atomicAdd(&cursor[d], 1);
    srcs[p] = eidx[t];
  }
}

// graph_ptr[g] = lower_bound(batch, g); batch is sorted
__global__ void k_graphptr(const int* __restrict__ batch, int* __restrict__ gp) {
  int g = threadIdx.x;
  if (g > Bg) return;
  int lo = 0, hi = Nn;
  while (lo < hi) {
    int mid = (lo + hi) >> 1;
    if (batch[mid] < g) lo = mid + 1; else hi = mid;
  }
  gp[g] = lo;
}

// ---------------------------------------------------------------------------
// transpose small weights once per launch (LSTM + W1)
// ---------------------------------------------------------------------------
__global__ void k_transpose(const float* __restrict__ W_ih,
                            const float* __restrict__ W_hh,
                            const float* __restrict__ W1,
                            float* __restrict__ WihT,   // [128][256]
                            float* __restrict__ WhhT,   // [64][256]
                            float* __restrict__ W1T) {  // [128][64]
  int idx = blockIdx.x * 256 + threadIdx.x;
  if (idx < 32768) {                 // W_ih [256][128]
    int row = idx / 128, k = idx % 128;
    WihT[k * 256 + row] = W_ih[idx];
  } else if (idx < 49152) {          // W_hh [256][64]
    int j = idx - 32768;
    int row = j / 64, k = j % 64;
    WhhT[k * 256 + row] = W_hh[j];
  } else if (idx < 57344) {          // W1 [64][128]
    int j = idx - 49152;
    int row = j / 128, k = j % 128;
    W1T[k * 64 + row] = W1[j];
  }
}

// fill x-columns of inp96 (cols 64..95), once per launch
__global__ void k_fillx(const float* __restrict__ x, float* __restrict__ inp96) {
  int idx = blockIdx.x * 256 + threadIdx.x;
  if (idx < Nn * DIN) {
    int n = idx / DIN, c = idx % DIN;
    inp96[(size_t)n * 96 + D + c] = x[idx];
  }
}

// ---------------------------------------------------------------------------
// CSR aggregate: inp96[n][0:64] = sum over in-edges of lin[src]
// ---------------------------------------------------------------------------
__global__ void k_aggregate(const int* __restrict__ rp, const int* __restrict__ srcs,
                            const float* __restrict__ lin, float* __restrict__ inp96) {
  int t = blockIdx.x * 256 + threadIdx.x;
  int n = t >> 4;
  int q = t & 15;
  int s = rp[n], e = rp[n + 1];
  float4 acc = {0.f, 0.f, 0.f, 0.f};
  for (int i = s; i < e; ++i) {
    int src = srcs[i];
    float4 v = *(const float4*)&lin[(size_t)src * 64 + q * 4];
    acc.x += v.x; acc.y += v.y; acc.z += v.z; acc.w += v.w;
  }
  *(float4*)&inp96[(size_t)n * 96 + q * 4] = acc;
}

// ---------------------------------------------------------------------------
// GRU combine: h' = (1-z)*tanh(gi_n + r*gh_n) + z*h
// ---------------------------------------------------------------------------
__global__ void k_combine(const float* __restrict__ gi, const float* __restrict__ gh,
                          const float* __restrict__ h, float* __restrict__ h2) {
  int idx = blockIdx.x * 256 + threadIdx.x;
  int n = idx >> 6, d = idx & 63;
  size_t b = (size_t)n * 192 + d;
  float gir = gi[b], giz = gi[b + 64], gin = gi[b + 128];
  float ghr = gh[b], ghz = gh[b + 64], ghn = gh[b + 128];
  float r = sigf(gir + ghr);
  float z = sigf(giz + ghz);
  float ng = tanhf(gin + r * ghn);
  h2[idx] = (1.f - z) * ng + z * h[idx];
}

// ---------------------------------------------------------------------------
// Set2Set phase 1: LSTM cell. One block per graph, one thread per gate row.
// ---------------------------------------------------------------------------
__global__ __launch_bounds__(256) void k_lstm(float* __restrict__ q_star,
                                              float* __restrict__ hl,
                                              float* __restrict__ cl,
                                              const float* __restrict__ WihT,
                                              const float* __restrict__ WhhT,
                                              const float* __restrict__ b_ih,
                                              const float* __restrict__ b_hh) {
  int g = blockIdx.x, t = threadIdx.x;
  __shared__ float qs[128], hsh[64], gates[256];
  if (t < 128) qs[t] = q_star[g * 128 + t];
  else if (t < 192) hsh[t - 128] = hl[g * 64 + (t - 128)];
  __syncthreads();
  float acc = b_ih[t] + b_hh[t];
  for (int k = 0; k < 128; ++k) acc = fmaf(WihT[k * 256 + t], qs[k], acc);
  for (int k = 0; k < 64; ++k)  acc = fmaf(WhhT[k * 256 + t], hsh[k], acc);
  gates[t] = acc;
  __syncthreads();
  if (t < 64) {
    float ig = sigf(gates[t]),       fg = sigf(gates[64 + t]);
    float gg = tanhf(gates[128 + t]), og = sigf(gates[192 + t]);
    float c = fg * cl[g * 64 + t] + ig * gg;
    float q = og * tanhf(c);
    cl[g * 64 + t] = c;
    hl[g * 64 + t] = q;
    q_star[g * 128 + t] = q;
  }
}

// ---------------------------------------------------------------------------
// Set2Set phase 2: e[n] = out[n] . q[batch[n]] for all nodes. No atomics.
// 16 threads per node, float4 per thread.
// ---------------------------------------------------------------------------
__global__ __launch_bounds__(256) void k_dot(const float* __restrict__ out,
                                             const float* __restrict__ q_star,
                                             const int* __restrict__ batch,
                                             float* __restrict__ e_buf) {
  int t = blockIdx.x * 256 + threadIdx.x;
  int n = t >> 4, q16 = t & 15;
  int g = batch[n];
  float4 o  = *(const float4*)&out[(size_t)n * 64 + q16 * 4];
  float4 qv = *(const float4*)&q_star[g * 128 + q16 * 4];
  float p = o.x * qv.x + o.y * qv.y + o.z * qv.z + o.w * qv.w;
  p += __shfl_xor(p, 1); p += __shfl_xor(p, 2);
  p += __shfl_xor(p, 4); p += __shfl_xor(p, 8);
  if (q16 == 0) e_buf[n] = p;
}

// ---------------------------------------------------------------------------
// Set2Set phase 3: per-graph segment max + softmax-weighted feature sum.
// One block per graph, 4 waves.
// ---------------------------------------------------------------------------
__global__ __launch_bounds__(256) void k_wsum(const float* __restrict__ out,
                                              const float* __restrict__ e_buf,
                                              const int* __restrict__ gp,
                                              float* __restrict__ q_star) {
  int g = blockIdx.x;
  int t = threadIdx.x;
  int w = t >> 6, lane = t & 63;
  __shared__ float wmax[4];
  __shared__ float partial[4][64];
  __shared__ float asum_p[4];
  __shared__ float emax_sh;
  int s = gp[g], e = gp[g + 1];

  // phase A: segment max of e_buf (replaces the old global atomicMax)
  float m = -INFINITY;
  for (int i = s + t; i < e; i += 256) m = fmaxf(m, e_buf[i]);
#pragma unroll
  for (int o = 32; o >= 1; o >>= 1) m = fmaxf(m, __shfl_xor(m, o));
  if (lane == 0) wmax[w] = m;
  __syncthreads();
  if (t == 0) {
    float mm = fmaxf(fmaxf(wmax[0], wmax[1]), fmaxf(wmax[2], wmax[3]));
    emax_sh = isfinite(mm) ? mm : 0.f;
  }
  __syncthreads();
  float emax = emax_sh;

  // phase B: weighted sum
  float acc = 0.f, asum = 0.f;
  for (int i = s + w; i < e; i += 4) {
    float a = expf(e_buf[i] - emax);
    asum += a;
    acc = fmaf(a, out[(size_t)i * 64 + lane], acc);
  }
  partial[w][lane] = acc;
  if (lane == 0) asum_p[w] = asum;
  __syncthreads();
  if (t < 64) {
    float r  = partial[0][t] + partial[1][t] + partial[2][t] + partial[3][t];
    float as = asum_p[0] + asum_p[1] + asum_p[2] + asum_p[3];
    q_star[g * 128 + 64 + t] = (e > s) ? r / fmaxf(as, 1e-16f) : 0.f;
  }
}

// ---------------------------------------------------------------------------
// Head: hid = relu(q_star @ W1^T + b1); logits = hid @ W2^T + b2; log_softmax
// ---------------------------------------------------------------------------
__global__ __launch_bounds__(64) void k_head(const float* __restrict__ q_star,
                                             const float* __restrict__ W1T,
                                             const float* __restrict__ b1,
                                             const float* __restrict__ W2,
                                             const float* __restrict__ b2,
                                             float* __restrict__ outp) {
  int g = blockIdx.x;
  int lane = threadIdx.x;
  __shared__ float qsh[128];
  __shared__ float hsh[64];
  __shared__ float l4[4];
  qsh[lane] = q_star[g * 128 + lane];
  qsh[64 + lane] = q_star[g * 128 + 64 + lane];
  __syncthreads();
  float acc = b1[lane];
  for (int k = 0; k < 128; ++k) acc = fmaf(W1T[k * 64 + lane], qsh[k], acc);
  hsh[lane] = fmaxf(acc, 0.f);
  __syncthreads();
  if (lane < 4) {
    float lg = b2[lane];
    for (int d = 0; d < 64; ++d) lg = fmaf(W2[lane * 64 + d], hsh[d], lg);
    l4[lane] = lg;
  }
  __syncthreads();
  if (lane < 4) {
    float m = fmaxf(fmaxf(l4[0], l4[1]), fmaxf(l4[2], l4[3]));
    float ssum = expf(l4[0] - m) + expf(l4[1] - m) + expf(l4[2] - m) + expf(l4[3] - m);
    outp[g * 4 + lane] = l4[lane] - m - logf(ssum);
  }
}

// ---------------------------------------------------------------------------
extern "C" void kernel_launch(void* const* d_in, const int* in_sizes, int n_in,
                              void* d_out, int out_size, void* d_ws, size_t ws_size,
                              hipStream_t stream) {
  const float* x        = (const float*)d_in[0];
  const int*   eidx     = (const int*)d_in[1];
  const int*   batch    = (const int*)d_in[2];
  const float* W_mlp    = (const float*)d_in[3];
  const float* b_mlp    = (const float*)d_in[4];
  const float* W_conv   = (const float*)d_in[5];
  const float* b_conv   = (const float*)d_in[6];
  const float* gW_ih    = (const float*)d_in[7];
  const float* gW_hh    = (const float*)d_in[8];
  const float* gb_ih    = (const float*)d_in[9];
  const float* gb_hh    = (const float*)d_in[10];
  const float* lW_ih    = (const float*)d_in[11];
  const float* lW_hh    = (const float*)d_in[12];
  const float* lb_ih    = (const float*)d_in[13];
  const float* lb_hh    = (const float*)d_in[14];
  const float* W1       = (const float*)d_in[15];
  const float* b1       = (const float*)d_in[16];
  const float* W2       = (const float*)d_in[17];
  const float* b2       = (const float*)d_in[18];
  float* outp = (float*)d_out;

  // ---- workspace layout ----
  char* ws = (char*)d_ws;
  size_t off = 0;
  auto alloc = [&](size_t bytes) { size_t r = off; off = (off + bytes + 255) & ~(size_t)255; return r; };
  float* outA  = (float*)(ws + alloc((size_t)Nn * 64 * 4));
  float* outB  = (float*)(ws + alloc((size_t)Nn * 64 * 4));
  float* inp96 = (float*)(ws + alloc((size_t)Nn * 96 * 4));
  float* gi    = (float*)(ws + alloc((size_t)Nn * 192 * 4));
  float* ghbuf = (float*)(ws + alloc((size_t)Nn * 192 * 4));  // lin aliases its head
  float* lin   = ghbuf;
  int*   count = (int*)(ws + alloc((size_t)Nn * 4));
  int*   rp    = (int*)(ws + alloc((size_t)(Nn + 1) * 4));
  int*   cursor= (int*)(ws + alloc((size_t)Nn * 4));
  int*   srcs  = (int*)(ws + alloc((size_t)Ne * 4));
  int*   gp    = (int*)(ws + alloc((size_t)(Bg + 1) * 4));
  float* e_buf = (float*)(ws + alloc((size_t)Nn * 4));
  float* WihT  = (float*)(ws + alloc((size_t)128 * 256 * 4));
  float* WhhT  = (float*)(ws + alloc((size_t)64 * 256 * 4));
  float* W1T   = (float*)(ws + alloc((size_t)128 * 64 * 4));
  float* s2s   = (float*)(ws + alloc((size_t)Bg * (128 + 64 + 64) * 4));  // q_star|hl|cl
  float* q_star = s2s;
  float* hl     = s2s + Bg * 128;
  float* cl     = s2s + Bg * 128 + Bg * 64;
  (void)in_sizes; (void)n_in; (void)out_size; (void)ws_size;

  // zero counters + set2set state
  hipMemsetAsync(count, 0, (size_t)Nn * 4, stream);
  hipMemsetAsync(s2s, 0, (size_t)Bg * 256 * 4, stream);

  // CSR build + small transposes + graph_ptr
  k_hist<<<Ne / 256, 256, 0, stream>>>(eidx, count);
  k_scan<<<1, 1024, 0, stream>>>(count, rp, cursor);
  k_place<<<Ne / 256, 256, 0, stream>>>(eidx, cursor, srcs);
  k_graphptr<<<1, 512, 0, stream>>>(batch, gp);
  k_transpose<<<224, 256, 0, stream>>>(lW_ih, lW_hh, W1, WihT, WhhT, W1T);

  // conv1: out = x @ W_mlp^T + b_mlp
  k_gemm<32, 64, 4><<<Nn / 128, 256, 0, stream>>>(x, W_mlp, b_mlp, outA);
  k_fillx<<<Nn * DIN / 256, 256, 0, stream>>>(x, inp96);

  float* h  = outA;
  float* h2 = outB;
  for (int step = 0; step < 2; ++step) {
    k_gemm<64, 64, 4><<<Nn / 128, 256, 0, stream>>>(h, W_conv, b_conv, lin);
    k_aggregate<<<Nn * 16 / 256, 256, 0, stream>>>(rp, srcs, lin, inp96);
    k_gemm<64, 192, 12><<<Nn / 128, 256, 0, stream>>>(h, gW_hh, gb_hh, ghbuf);
    k_gemm<96, 192, 12><<<Nn / 128, 256, 0, stream>>>(inp96, gW_ih, gb_ih, gi);
    k_combine<<<Nn * 64 / 256, 256, 0, stream>>>(gi, ghbuf, h, h2);
    float* tmp = h; h = h2; h2 = tmp;
  }
  // h now points to final node features

  for (int it = 0; it < 3; ++it) {
    k_lstm<<<Bg, 256, 0, stream>>>(q_star, hl, cl, WihT, WhhT, lb_ih, lb_hh);
    k_dot<<<Nn * 16 / 256, 256, 0, stream>>>(h, q_star, batch, e_buf);
    k_wsum<<<Bg, 256, 0, stream>>>(h, e_buf, gp, q_star);
  }
  k_head<<<Bg, 64, 0, stream>>>(q_star, W1T, b1, W2, b2, outp);
}

// Round 4
// 602.920 us; speedup vs baseline: 1.9671x; 1.2535x over previous
//
#include <hip/hip_runtime.h>
#include <math.h>

constexpr int Nn  = 65536;    // nodes
constexpr int Ne  = 1048576;  // edges
constexpr int Bg  = 256;      // graphs
constexpr int DIN = 32;
constexpr int D   = 64;

typedef __attribute__((ext_vector_type(8))) short bf16x8;
typedef __attribute__((ext_vector_type(4))) float f32x4;

__device__ __forceinline__ float sigf(float x) { return 1.0f / (1.0f + expf(-x)); }

// ---- bf16 split helpers (RNE) ----
__device__ __forceinline__ unsigned short bf16_rne(float f) {
  unsigned u = __float_as_uint(f);
  unsigned r = u + 0x7FFFu + ((u >> 16) & 1u);
  return (unsigned short)(r >> 16);
}
__device__ __forceinline__ float bf16_tof(unsigned short h) {
  return __uint_as_float(((unsigned)h) << 16);
}
__device__ __forceinline__ void split2(float f, unsigned short& hi, unsigned short& lo) {
  hi = bf16_rne(f);
  lo = bf16_rne(f - bf16_tof(hi));
}

#define MFMA(a, b, c) __builtin_amdgcn_mfma_f32_16x16x32_bf16(a, b, c, 0, 0, 0)

// ---------------------------------------------------------------------------
// Weight fragment packing.  For GEMM C[m][n] = sum_k A[m][k] * W[n][k]:
// B-fragment element j of lane L (quad=L>>4): B[k=ks*32+quad*8+j][n=nt*16+(L&15)]
// pack index p = ((nt*KS + ks)*64 + L)*8 + j   (separate hi/lo planes)
// Matrices: W_mlp(64x32,KS1,NT4) W_conv(64x64,KS2,NT4) gWih(192x96,KS3,NT12)
//           gWhh(192x64,KS2,NT12).  Totals/plane: 2048,4096,18432,12288.
// ---------------------------------------------------------------------------
__global__ void k_packw(const float* __restrict__ W_mlp, const float* __restrict__ W_conv,
                        const float* __restrict__ gWih, const float* __restrict__ gWhh,
                        unsigned short* __restrict__ mlp_h, unsigned short* __restrict__ mlp_l,
                        unsigned short* __restrict__ cv_h,  unsigned short* __restrict__ cv_l,
                        unsigned short* __restrict__ ih_h,  unsigned short* __restrict__ ih_l,
                        unsigned short* __restrict__ hh_h,  unsigned short* __restrict__ hh_l) {
  int p = blockIdx.x * 256 + threadIdx.x;
  if (p >= 36864) return;
  const float* W; int K, KS; unsigned short *oh, *ol; int lp = p;
  if (p < 2048)       { W = W_mlp;  K = 32; KS = 1; oh = mlp_h; ol = mlp_l; }
  else if (p < 6144)  { W = W_conv; K = 64; KS = 2; oh = cv_h;  ol = cv_l;  lp -= 2048; }
  else if (p < 24576) { W = gWih;   K = 96; KS = 3; oh = ih_h;  ol = ih_l;  lp -= 6144; }
  else                { W = gWhh;   K = 64; KS = 2; oh = hh_h;  ol = hh_l;  lp -= 24576; }
  int j = lp & 7, lane = (lp >> 3) & 63, q = lp >> 9;
  int ks = q % KS, nt = q / KS;
  int n = nt * 16 + (lane & 15);
  int k = ks * 32 + (lane >> 4) * 8 + j;
  unsigned short hi, lo;
  split2(W[n * K + k], hi, lo);
  oh[lp] = hi; ol[lp] = lo;
}

// ---------------------------------------------------------------------------
// x prep: split x into planes for conv1 (stride 32) and inp96 cols 64..95
// ---------------------------------------------------------------------------
__global__ void k_prepx(const float* __restrict__ x,
                        unsigned short* __restrict__ Axh, unsigned short* __restrict__ Axl,
                        unsigned short* __restrict__ Aih, unsigned short* __restrict__ Ail) {
  int idx = blockIdx.x * 256 + threadIdx.x;
  if (idx >= Nn * DIN) return;
  int n = idx >> 5, c = idx & 31;
  unsigned short hi, lo;
  split2(x[idx], hi, lo);
  Axh[idx] = hi; Axl[idx] = lo;
  Aih[(size_t)n * 96 + 64 + c] = hi;
  Ail[(size_t)n * 96 + 64 + c] = lo;
}

// ---------------------------------------------------------------------------
// conv1: h = x @ W_mlp^T + b   (K=32, N=64).  Writes h fp32 + split planes.
// ---------------------------------------------------------------------------
__global__ __launch_bounds__(256) void k_conv1(const unsigned short* __restrict__ Axh,
                                               const unsigned short* __restrict__ Axl,
                                               const unsigned short* __restrict__ Wh,
                                               const unsigned short* __restrict__ Wl,
                                               const float* __restrict__ bias,
                                               float* __restrict__ h,
                                               unsigned short* __restrict__ hph,
                                               unsigned short* __restrict__ hpl) {
  int wave = threadIdx.x >> 6, lane = threadIdx.x & 63;
  int quad = lane >> 4;
  int n0w = blockIdx.x * 64 + wave * 16;
  int rowA = n0w + (lane & 15);
  f32x4 acc[4] = {};
  bf16x8 ah = *(const bf16x8*)&Axh[(size_t)rowA * 32 + quad * 8];
  bf16x8 al = *(const bf16x8*)&Axl[(size_t)rowA * 32 + quad * 8];
#pragma unroll
  for (int nt = 0; nt < 4; ++nt) {
    bf16x8 bh = *(const bf16x8*)&Wh[(nt * 64 + lane) * 8];
    bf16x8 bl = *(const bf16x8*)&Wl[(nt * 64 + lane) * 8];
    acc[nt] = MFMA(ah, bh, acc[nt]);
    acc[nt] = MFMA(ah, bl, acc[nt]);
    acc[nt] = MFMA(al, bh, acc[nt]);
  }
  int col0 = lane & 15;
#pragma unroll
  for (int nt = 0; nt < 4; ++nt) {
    float bv = bias[nt * 16 + col0];
#pragma unroll
    for (int r = 0; r < 4; ++r) {
      int node = n0w + quad * 4 + r;
      float v = acc[nt][r] + bv;
      size_t o = (size_t)node * 64 + nt * 16 + col0;
      h[o] = v;
      unsigned short hi, lo; split2(v, hi, lo);
      hph[o] = hi; hpl[o] = lo;
    }
  }
}

// ---------------------------------------------------------------------------
// lin = h @ W_conv^T + b  (K=64, N=64).  fp32 out only (feeds fp32 aggregate).
// ---------------------------------------------------------------------------
__global__ __launch_bounds__(256) void k_lin(const unsigned short* __restrict__ Ah,
                                             const unsigned short* __restrict__ Al,
                                             const unsigned short* __restrict__ Wh,
                                             const unsigned short* __restrict__ Wl,
                                             const float* __restrict__ bias,
                                             float* __restrict__ lin) {
  int wave = threadIdx.x >> 6, lane = threadIdx.x & 63;
  int quad = lane >> 4;
  int n0w = blockIdx.x * 64 + wave * 16;
  int rowA = n0w + (lane & 15);
  f32x4 acc[4] = {};
#pragma unroll
  for (int ks = 0; ks < 2; ++ks) {
    bf16x8 ah = *(const bf16x8*)&Ah[(size_t)rowA * 64 + ks * 32 + quad * 8];
    bf16x8 al = *(const bf16x8*)&Al[(size_t)rowA * 64 + ks * 32 + quad * 8];
#pragma unroll
    for (int nt = 0; nt < 4; ++nt) {
      bf16x8 bh = *(const bf16x8*)&Wh[((nt * 2 + ks) * 64 + lane) * 8];
      bf16x8 bl = *(const bf16x8*)&Wl[((nt * 2 + ks) * 64 + lane) * 8];
      acc[nt] = MFMA(ah, bh, acc[nt]);
      acc[nt] = MFMA(ah, bl, acc[nt]);
      acc[nt] = MFMA(al, bh, acc[nt]);
    }
  }
  int col0 = lane & 15;
#pragma unroll
  for (int nt = 0; nt < 4; ++nt) {
    float bv = bias[nt * 16 + col0];
#pragma unroll
    for (int r = 0; r < 4; ++r) {
      int node = n0w + quad * 4 + r;
      lin[(size_t)node * 64 + nt * 16 + col0] = acc[nt][r] + bv;
    }
  }
}

// ---------------------------------------------------------------------------
// Fused GRU step: gi = inp96 @ Wih^T + b_ih (K=96), gh = h @ Whh^T + b_hh (K=64),
// then h2 = (1-z)*tanh(gi_n + r*gh_n) + z*h.  Writes h2 fp32 + split planes.
// ---------------------------------------------------------------------------
__global__ __launch_bounds__(256) void k_gru(const unsigned short* __restrict__ Aih,
                                             const unsigned short* __restrict__ Ail,
                                             const unsigned short* __restrict__ Hh,
                                             const unsigned short* __restrict__ Hl,
                                             const unsigned short* __restrict__ Wih_h,
                                             const unsigned short* __restrict__ Wih_l,
                                             const unsigned short* __restrict__ Whh_h,
                                             const unsigned short* __restrict__ Whh_l,
                                             const float* __restrict__ b_ih,
                                             const float* __restrict__ b_hh,
                                             const float* __restrict__ h_old,
                                             float* __restrict__ h_new,
                                             unsigned short* __restrict__ hph,
                                             unsigned short* __restrict__ hpl) {
  int wave = threadIdx.x >> 6, lane = threadIdx.x & 63;
  int quad = lane >> 4;
  int n0w = blockIdx.x * 64 + wave * 16;
  int rowA = n0w + (lane & 15);
  f32x4 accI[12] = {};
  f32x4 accH[12] = {};
  // gi: K = 96, 3 k-steps
#pragma unroll
  for (int ks = 0; ks < 3; ++ks) {
    bf16x8 ah = *(const bf16x8*)&Aih[(size_t)rowA * 96 + ks * 32 + quad * 8];
    bf16x8 al = *(const bf16x8*)&Ail[(size_t)rowA * 96 + ks * 32 + quad * 8];
#pragma unroll
    for (int nt = 0; nt < 12; ++nt) {
      bf16x8 bh = *(const bf16x8*)&Wih_h[((nt * 3 + ks) * 64 + lane) * 8];
      bf16x8 bl = *(const bf16x8*)&Wih_l[((nt * 3 + ks) * 64 + lane) * 8];
      accI[nt] = MFMA(ah, bh, accI[nt]);
      accI[nt] = MFMA(ah, bl, accI[nt]);
      accI[nt] = MFMA(al, bh, accI[nt]);
    }
  }
  // gh: K = 64, 2 k-steps
#pragma unroll
  for (int ks = 0; ks < 2; ++ks) {
    bf16x8 ah = *(const bf16x8*)&Hh[(size_t)rowA * 64 + ks * 32 + quad * 8];
    bf16x8 al = *(const bf16x8*)&Hl[(size_t)rowA * 64 + ks * 32 + quad * 8];
#pragma unroll
    for (int nt = 0; nt < 12; ++nt) {
      bf16x8 bh = *(const bf16x8*)&Whh_h[((nt * 2 + ks) * 64 + lane) * 8];
      bf16x8 bl = *(const bf16x8*)&Whh_l[((nt * 2 + ks) * 64 + lane) * 8];
      accH[nt] = MFMA(ah, bh, accH[nt]);
      accH[nt] = MFMA(ah, bl, accH[nt]);
      accH[nt] = MFMA(al, bh, accH[nt]);
    }
  }
  int col0 = lane & 15;
#pragma unroll
  for (int nt = 0; nt < 4; ++nt) {
    float bir = b_ih[nt * 16 + col0],        bhr = b_hh[nt * 16 + col0];
    float biz = b_ih[64 + nt * 16 + col0],   bhz = b_hh[64 + nt * 16 + col0];
    float bin = b_ih[128 + nt * 16 + col0],  bhn = b_hh[128 + nt * 16 + col0];
#pragma unroll
    for (int r = 0; r < 4; ++r) {
      int node = n0w + quad * 4 + r;
      size_t o = (size_t)node * 64 + nt * 16 + col0;
      float rr = sigf(accI[nt][r] + bir + accH[nt][r] + bhr);
      float zz = sigf(accI[nt + 4][r] + biz + accH[nt + 4][r] + bhz);
      float nn = tanhf(accI[nt + 8][r] + bin + rr * (accH[nt + 8][r] + bhn));
      float hv = (1.f - zz) * nn + zz * h_old[o];
      h_new[o] = hv;
      unsigned short hi, lo; split2(hv, hi, lo);
      hph[o] = hi; hpl[o] = lo;
    }
  }
}

// ---------------------------------------------------------------------------
// CSR build: histogram over dst, 1-block scan, placement
// ---------------------------------------------------------------------------
__global__ void k_hist(const int* __restrict__ eidx, int* __restrict__ count) {
  int t = blockIdx.x * 256 + threadIdx.x;
  if (t < Ne) atomicAdd(&count[eidx[Ne + t]], 1);
}

__global__ __launch_bounds__(1024) void k_scan(const int* __restrict__ count,
                                               int* __restrict__ rp,
                                               int* __restrict__ cursor) {
  __shared__ int sh[1024];
  int t = threadIdx.x;
  int base = t * 64;
  int sum = 0;
  for (int i = 0; i < 64; ++i) sum += count[base + i];
  sh[t] = sum;
  __syncthreads();
  for (int off = 1; off < 1024; off <<= 1) {
    int v = (t >= off) ? sh[t - off] : 0;
    __syncthreads();
    sh[t] += v;
    __syncthreads();
  }
  int run = (t == 0) ? 0 : sh[t - 1];
  for (int i = 0; i < 64; ++i) {
    int c = count[base + i];
    rp[base + i] = run;
    cursor[base + i] = run;
    run += c;
  }
  if (t == 1023) rp[Nn] = run;
}

__global__ void k_place(const int* __restrict__ eidx, int* __restrict__ cursor,
                        int* __restrict__ srcs) {
  int t = blockIdx.x * 256 + threadIdx.x;
  if (t < Ne) {
    int d = eidx[Ne + t];
    int p = atomicAdd(&cursor[d], 1);
    srcs[p] = eidx[t];
  }
}

__global__ void k_graphptr(const int* __restrict__ batch, int* __restrict__ gp) {
  int g = threadIdx.x;
  if (g > Bg) return;
  int lo = 0, hi = Nn;
  while (lo < hi) {
    int mid = (lo + hi) >> 1;
    if (batch[mid] < g) lo = mid + 1; else hi = mid;
  }
  gp[g] = lo;
}

// ---------------------------------------------------------------------------
// transpose small weights once per launch (LSTM + W1)
// ---------------------------------------------------------------------------
__global__ void k_transpose(const float* __restrict__ W_ih,
                            const float* __restrict__ W_hh,
                            const float* __restrict__ W1,
                            float* __restrict__ WihT,   // [128][256]
                            float* __restrict__ WhhT,   // [64][256]
                            float* __restrict__ W1T) {  // [128][64]
  int idx = blockIdx.x * 256 + threadIdx.x;
  if (idx < 32768) {
    int row = idx / 128, k = idx % 128;
    WihT[k * 256 + row] = W_ih[idx];
  } else if (idx < 49152) {
    int j = idx - 32768;
    int row = j / 64, k = j % 64;
    WhhT[k * 256 + row] = W_hh[j];
  } else if (idx < 57344) {
    int j = idx - 49152;
    int row = j / 128, k = j % 128;
    W1T[k * 64 + row] = W1[j];
  }
}

// ---------------------------------------------------------------------------
// CSR aggregate: m[n] = sum over in-edges of lin[src]; writes split planes
// into inp96 cols 0..63.
// ---------------------------------------------------------------------------
__global__ void k_aggregate(const int* __restrict__ rp, const int* __restrict__ srcs,
                            const float* __restrict__ lin,
                            unsigned short* __restrict__ Aih,
                            unsigned short* __restrict__ Ail) {
  int t = blockIdx.x * 256 + threadIdx.x;
  int n = t >> 4;
  int q = t & 15;
  int s = rp[n], e = rp[n + 1];
  float4 acc = {0.f, 0.f, 0.f, 0.f};
  for (int i = s; i < e; ++i) {
    int src = srcs[i];
    float4 v = *(const float4*)&lin[(size_t)src * 64 + q * 4];
    acc.x += v.x; acc.y += v.y; acc.z += v.z; acc.w += v.w;
  }
  ushort4 h4, l4;
  split2(acc.x, h4.x, l4.x);
  split2(acc.y, h4.y, l4.y);
  split2(acc.z, h4.z, l4.z);
  split2(acc.w, h4.w, l4.w);
  *(ushort4*)&Aih[(size_t)n * 96 + q * 4] = h4;
  *(ushort4*)&Ail[(size_t)n * 96 + q * 4] = l4;
}

// ---------------------------------------------------------------------------
// Set2Set phase 1: LSTM cell. One block per graph, one thread per gate row.
// ---------------------------------------------------------------------------
__global__ __launch_bounds__(256) void k_lstm(float* __restrict__ q_star,
                                              float* __restrict__ hl,
                                              float* __restrict__ cl,
                                              const float* __restrict__ WihT,
                                              const float* __restrict__ WhhT,
                                              const float* __restrict__ b_ih,
                                              const float* __restrict__ b_hh) {
  int g = blockIdx.x, t = threadIdx.x;
  __shared__ float qs[128], hsh[64], gates[256];
  if (t < 128) qs[t] = q_star[g * 128 + t];
  else if (t < 192) hsh[t - 128] = hl[g * 64 + (t - 128)];
  __syncthreads();
  float acc = b_ih[t] + b_hh[t];
  for (int k = 0; k < 128; ++k) acc = fmaf(WihT[k * 256 + t], qs[k], acc);
  for (int k = 0; k < 64; ++k)  acc = fmaf(WhhT[k * 256 + t], hsh[k], acc);
  gates[t] = acc;
  __syncthreads();
  if (t < 64) {
    float ig = sigf(gates[t]),        fg = sigf(gates[64 + t]);
    float gg = tanhf(gates[128 + t]), og = sigf(gates[192 + t]);
    float c = fg * cl[g * 64 + t] + ig * gg;
    float q = og * tanhf(c);
    cl[g * 64 + t] = c;
    hl[g * 64 + t] = q;
    q_star[g * 128 + t] = q;
  }
}

// ---------------------------------------------------------------------------
// Set2Set phase 2: e[n] = out[n] . q[batch[n]], no atomics
// ---------------------------------------------------------------------------
__global__ __launch_bounds__(256) void k_dot(const float* __restrict__ out,
                                             const float* __restrict__ q_star,
                                             const int* __restrict__ batch,
                                             float* __restrict__ e_buf) {
  int t = blockIdx.x * 256 + threadIdx.x;
  int n = t >> 4, q16 = t & 15;
  int g = batch[n];
  float4 o  = *(const float4*)&out[(size_t)n * 64 + q16 * 4];
  float4 qv = *(const float4*)&q_star[g * 128 + q16 * 4];
  float p = o.x * qv.x + o.y * qv.y + o.z * qv.z + o.w * qv.w;
  p += __shfl_xor(p, 1); p += __shfl_xor(p, 2);
  p += __shfl_xor(p, 4); p += __shfl_xor(p, 8);
  if (q16 == 0) e_buf[n] = p;
}

// ---------------------------------------------------------------------------
// Set2Set phase 3: per-graph segment max + softmax-weighted feature sum
// ---------------------------------------------------------------------------
__global__ __launch_bounds__(256) void k_wsum(const float* __restrict__ out,
                                              const float* __restrict__ e_buf,
                                              const int* __restrict__ gp,
                                              float* __restrict__ q_star) {
  int g = blockIdx.x;
  int t = threadIdx.x;
  int w = t >> 6, lane = t & 63;
  __shared__ float wmax[4];
  __shared__ float partial[4][64];
  __shared__ float asum_p[4];
  __shared__ float emax_sh;
  int s = gp[g], e = gp[g + 1];

  float m = -INFINITY;
  for (int i = s + t; i < e; i += 256) m = fmaxf(m, e_buf[i]);
#pragma unroll
  for (int o = 32; o >= 1; o >>= 1) m = fmaxf(m, __shfl_xor(m, o));
  if (lane == 0) wmax[w] = m;
  __syncthreads();
  if (t == 0) {
    float mm = fmaxf(fmaxf(wmax[0], wmax[1]), fmaxf(wmax[2], wmax[3]));
    emax_sh = isfinite(mm) ? mm : 0.f;
  }
  __syncthreads();
  float emax = emax_sh;

  float acc = 0.f, asum = 0.f;
  for (int i = s + w; i < e; i += 4) {
    float a = expf(e_buf[i] - emax);
    asum += a;
    acc = fmaf(a, out[(size_t)i * 64 + lane], acc);
  }
  partial[w][lane] = acc;
  if (lane == 0) asum_p[w] = asum;
  __syncthreads();
  if (t < 64) {
    float r  = partial[0][t] + partial[1][t] + partial[2][t] + partial[3][t];
    float as = asum_p[0] + asum_p[1] + asum_p[2] + asum_p[3];
    q_star[g * 128 + 64 + t] = (e > s) ? r / fmaxf(as, 1e-16f) : 0.f;
  }
}

// ---------------------------------------------------------------------------
// Head
// ---------------------------------------------------------------------------
__global__ __launch_bounds__(64) void k_head(const float* __restrict__ q_star,
                                             const float* __restrict__ W1T,
                                             const float* __restrict__ b1,
                                             const float* __restrict__ W2,
                                             const float* __restrict__ b2,
                                             float* __restrict__ outp) {
  int g = blockIdx.x;
  int lane = threadIdx.x;
  __shared__ float qsh[128];
  __shared__ float hsh[64];
  __shared__ float l4[4];
  qsh[lane] = q_star[g * 128 + lane];
  qsh[64 + lane] = q_star[g * 128 + 64 + lane];
  __syncthreads();
  float acc = b1[lane];
  for (int k = 0; k < 128; ++k) acc = fmaf(W1T[k * 64 + lane], qsh[k], acc);
  hsh[lane] = fmaxf(acc, 0.f);
  __syncthreads();
  if (lane < 4) {
    float lg = b2[lane];
    for (int d = 0; d < 64; ++d) lg = fmaf(W2[lane * 64 + d], hsh[d], lg);
    l4[lane] = lg;
  }
  __syncthreads();
  if (lane < 4) {
    float m = fmaxf(fmaxf(l4[0], l4[1]), fmaxf(l4[2], l4[3]));
    float ssum = expf(l4[0] - m) + expf(l4[1] - m) + expf(l4[2] - m) + expf(l4[3] - m);
    outp[g * 4 + lane] = l4[lane] - m - logf(ssum);
  }
}

// ---------------------------------------------------------------------------
extern "C" void kernel_launch(void* const* d_in, const int* in_sizes, int n_in,
                              void* d_out, int out_size, void* d_ws, size_t ws_size,
                              hipStream_t stream) {
  const float* x        = (const float*)d_in[0];
  const int*   eidx     = (const int*)d_in[1];
  const int*   batch    = (const int*)d_in[2];
  const float* W_mlp    = (const float*)d_in[3];
  const float* b_mlp    = (const float*)d_in[4];
  const float* W_conv   = (const float*)d_in[5];
  const float* b_conv   = (const float*)d_in[6];
  const float* gW_ih    = (const float*)d_in[7];
  const float* gW_hh    = (const float*)d_in[8];
  const float* gb_ih    = (const float*)d_in[9];
  const float* gb_hh    = (const float*)d_in[10];
  const float* lW_ih    = (const float*)d_in[11];
  const float* lW_hh    = (const float*)d_in[12];
  const float* lb_ih    = (const float*)d_in[13];
  const float* lb_hh    = (const float*)d_in[14];
  const float* W1       = (const float*)d_in[15];
  const float* b1       = (const float*)d_in[16];
  const float* W2       = (const float*)d_in[17];
  const float* b2       = (const float*)d_in[18];
  float* outp = (float*)d_out;

  // ---- workspace layout ----
  char* ws = (char*)d_ws;
  size_t off = 0;
  auto alloc = [&](size_t bytes) { size_t r = off; off = (off + bytes + 255) & ~(size_t)255; return r; };
  float* hA  = (float*)(ws + alloc((size_t)Nn * 64 * 4));
  float* hB  = (float*)(ws + alloc((size_t)Nn * 64 * 4));
  unsigned short* hpAh = (unsigned short*)(ws + alloc((size_t)Nn * 64 * 2));
  unsigned short* hpAl = (unsigned short*)(ws + alloc((size_t)Nn * 64 * 2));
  unsigned short* hpBh = (unsigned short*)(ws + alloc((size_t)Nn * 64 * 2));
  unsigned short* hpBl = (unsigned short*)(ws + alloc((size_t)Nn * 64 * 2));
  unsigned short* Axh  = (unsigned short*)(ws + alloc((size_t)Nn * 32 * 2));
  unsigned short* Axl  = (unsigned short*)(ws + alloc((size_t)Nn * 32 * 2));
  unsigned short* Aih  = (unsigned short*)(ws + alloc((size_t)Nn * 96 * 2));
  unsigned short* Ail  = (unsigned short*)(ws + alloc((size_t)Nn * 96 * 2));
  float* lin   = (float*)(ws + alloc((size_t)Nn * 64 * 4));
  int*   count = (int*)(ws + alloc((size_t)Nn * 4));
  int*   rp    = (int*)(ws + alloc((size_t)(Nn + 1) * 4));
  int*   cursor= (int*)(ws + alloc((size_t)Nn * 4));
  int*   srcs  = (int*)(ws + alloc((size_t)Ne * 4));
  int*   gp    = (int*)(ws + alloc((size_t)(Bg + 1) * 4));
  float* e_buf = (float*)(ws + alloc((size_t)Nn * 4));
  float* WihT  = (float*)(ws + alloc((size_t)128 * 256 * 4));
  float* WhhT  = (float*)(ws + alloc((size_t)64 * 256 * 4));
  float* W1T   = (float*)(ws + alloc((size_t)128 * 64 * 4));
  unsigned short* mlp_h = (unsigned short*)(ws + alloc(2048 * 2));
  unsigned short* mlp_l = (unsigned short*)(ws + alloc(2048 * 2));
  unsigned short* cv_h  = (unsigned short*)(ws + alloc(4096 * 2));
  unsigned short* cv_l  = (unsigned short*)(ws + alloc(4096 * 2));
  unsigned short* ih_h  = (unsigned short*)(ws + alloc(18432 * 2));
  unsigned short* ih_l  = (unsigned short*)(ws + alloc(18432 * 2));
  unsigned short* hh_h  = (unsigned short*)(ws + alloc(12288 * 2));
  unsigned short* hh_l  = (unsigned short*)(ws + alloc(12288 * 2));
  float* s2s   = (float*)(ws + alloc((size_t)Bg * (128 + 64 + 64) * 4));
  float* q_star = s2s;
  float* hl     = s2s + Bg * 128;
  float* cl     = s2s + Bg * 128 + Bg * 64;
  (void)in_sizes; (void)n_in; (void)out_size; (void)ws_size;

  hipMemsetAsync(count, 0, (size_t)Nn * 4, stream);
  hipMemsetAsync(s2s, 0, (size_t)Bg * 256 * 4, stream);

  // CSR build + small packs
  k_hist<<<Ne / 256, 256, 0, stream>>>(eidx, count);
  k_scan<<<1, 1024, 0, stream>>>(count, rp, cursor);
  k_place<<<Ne / 256, 256, 0, stream>>>(eidx, cursor, srcs);
  k_graphptr<<<1, 512, 0, stream>>>(batch, gp);
  k_transpose<<<224, 256, 0, stream>>>(lW_ih, lW_hh, W1, WihT, WhhT, W1T);
  k_packw<<<144, 256, 0, stream>>>(W_mlp, W_conv, gW_ih, gW_hh,
                                   mlp_h, mlp_l, cv_h, cv_l, ih_h, ih_l, hh_h, hh_l);
  k_prepx<<<Nn * DIN / 256, 256, 0, stream>>>(x, Axh, Axl, Aih, Ail);

  // conv1
  k_conv1<<<Nn / 64, 256, 0, stream>>>(Axh, Axl, mlp_h, mlp_l, b_mlp, hA, hpAh, hpAl);

  float* h = hA; float* h2 = hB;
  unsigned short *cph = hpAh, *cpl = hpAl, *nph = hpBh, *npl = hpBl;
  for (int step = 0; step < 2; ++step) {
    k_lin<<<Nn / 64, 256, 0, stream>>>(cph, cpl, cv_h, cv_l, b_conv, lin);
    k_aggregate<<<Nn * 16 / 256, 256, 0, stream>>>(rp, srcs, lin, Aih, Ail);
    k_gru<<<Nn / 64, 256, 0, stream>>>(Aih, Ail, cph, cpl, ih_h, ih_l, hh_h, hh_l,
                                       gb_ih, gb_hh, h, h2, nph, npl);
    float* tf = h; h = h2; h2 = tf;
    unsigned short* tu;
    tu = cph; cph = nph; nph = tu;
    tu = cpl; cpl = npl; npl = tu;
  }

  for (int it = 0; it < 3; ++it) {
    k_lstm<<<Bg, 256, 0, stream>>>(q_star, hl, cl, WihT, WhhT, lb_ih, lb_hh);
    k_dot<<<Nn * 16 / 256, 256, 0, stream>>>(h, q_star, batch, e_buf);
    k_wsum<<<Bg, 256, 0, stream>>>(h, e_buf, gp, q_star);
  }
  k_head<<<Bg, 64, 0, stream>>>(q_star, W1T, b1, W2, b2, outp);
}

// Round 5
// 535.427 us; speedup vs baseline: 2.2150x; 1.1261x over previous
//
#include <hip/hip_runtime.h>
#include <math.h>

constexpr int Nn  = 65536;    // nodes
constexpr int Ne  = 1048576;  // edges
constexpr int Bg  = 256;      // graphs
constexpr int DIN = 32;
constexpr int D   = 64;

typedef __attribute__((ext_vector_type(8))) short bf16x8;
typedef __attribute__((ext_vector_type(4))) float f32x4;

__device__ __forceinline__ float sigf(float x) { return 1.0f / (1.0f + expf(-x)); }

// ---- bf16 split helpers (RNE) ----
__device__ __forceinline__ unsigned short bf16_rne(float f) {
  unsigned u = __float_as_uint(f);
  unsigned r = u + 0x7FFFu + ((u >> 16) & 1u);
  return (unsigned short)(r >> 16);
}
__device__ __forceinline__ float bf16_tof(unsigned short h) {
  return __uint_as_float(((unsigned)h) << 16);
}
__device__ __forceinline__ void split2(float f, unsigned short& hi, unsigned short& lo) {
  hi = bf16_rne(f);
  lo = bf16_rne(f - bf16_tof(hi));
}

#define MFMA(a, b, c) __builtin_amdgcn_mfma_f32_16x16x32_bf16(a, b, c, 0, 0, 0)

// ---------------------------------------------------------------------------
// Weight fragment packing (unchanged from round 4).
// pack index p = ((nt*KS + ks)*64 + L)*8 + j  (separate hi/lo planes)
// ---------------------------------------------------------------------------
__global__ void k_packw(const float* __restrict__ W_mlp, const float* __restrict__ W_conv,
                        const float* __restrict__ gWih, const float* __restrict__ gWhh,
                        unsigned short* __restrict__ mlp_h, unsigned short* __restrict__ mlp_l,
                        unsigned short* __restrict__ cv_h,  unsigned short* __restrict__ cv_l,
                        unsigned short* __restrict__ ih_h,  unsigned short* __restrict__ ih_l,
                        unsigned short* __restrict__ hh_h,  unsigned short* __restrict__ hh_l) {
  int p = blockIdx.x * 256 + threadIdx.x;
  if (p >= 36864) return;
  const float* W; int K, KS; unsigned short *oh, *ol; int lp = p;
  if (p < 2048)       { W = W_mlp;  K = 32; KS = 1; oh = mlp_h; ol = mlp_l; }
  else if (p < 6144)  { W = W_conv; K = 64; KS = 2; oh = cv_h;  ol = cv_l;  lp -= 2048; }
  else if (p < 24576) { W = gWih;   K = 96; KS = 3; oh = ih_h;  ol = ih_l;  lp -= 6144; }
  else                { W = gWhh;   K = 64; KS = 2; oh = hh_h;  ol = hh_l;  lp -= 24576; }
  int j = lp & 7, lane = (lp >> 3) & 63, q = lp >> 9;
  int ks = q % KS, nt = q / KS;
  int n = nt * 16 + (lane & 15);
  int k = ks * 32 + (lane >> 4) * 8 + j;
  unsigned short hi, lo;
  split2(W[n * K + k], hi, lo);
  oh[lp] = hi; ol[lp] = lo;
}

// ---------------------------------------------------------------------------
// x prep: split x into planes for conv1 (stride 32) and inp96 cols 64..95
// ---------------------------------------------------------------------------
__global__ void k_prepx(const float* __restrict__ x,
                        unsigned short* __restrict__ Axh, unsigned short* __restrict__ Axl,
                        unsigned short* __restrict__ Aih, unsigned short* __restrict__ Ail) {
  int idx = blockIdx.x * 256 + threadIdx.x;
  if (idx >= Nn * DIN) return;
  int n = idx >> 5, c = idx & 31;
  unsigned short hi, lo;
  split2(x[idx], hi, lo);
  Axh[idx] = hi; Axl[idx] = lo;
  Aih[(size_t)n * 96 + 64 + c] = hi;
  Ail[(size_t)n * 96 + 64 + c] = lo;
}

// ---------------------------------------------------------------------------
// conv1: h = x @ W_mlp^T + b   (K=32, N=64).  Writes h fp32 + split planes.
// ---------------------------------------------------------------------------
__global__ __launch_bounds__(256) void k_conv1(const unsigned short* __restrict__ Axh,
                                               const unsigned short* __restrict__ Axl,
                                               const unsigned short* __restrict__ Wh,
                                               const unsigned short* __restrict__ Wl,
                                               const float* __restrict__ bias,
                                               float* __restrict__ h,
                                               unsigned short* __restrict__ hph,
                                               unsigned short* __restrict__ hpl) {
  int wave = threadIdx.x >> 6, lane = threadIdx.x & 63;
  int quad = lane >> 4;
  int n0w = blockIdx.x * 64 + wave * 16;
  int rowA = n0w + (lane & 15);
  f32x4 acc[4] = {};
  bf16x8 ah = *(const bf16x8*)&Axh[(size_t)rowA * 32 + quad * 8];
  bf16x8 al = *(const bf16x8*)&Axl[(size_t)rowA * 32 + quad * 8];
#pragma unroll
  for (int nt = 0; nt < 4; ++nt) {
    bf16x8 bh = *(const bf16x8*)&Wh[(nt * 64 + lane) * 8];
    bf16x8 bl = *(const bf16x8*)&Wl[(nt * 64 + lane) * 8];
    acc[nt] = MFMA(ah, bh, acc[nt]);
    acc[nt] = MFMA(ah, bl, acc[nt]);
    acc[nt] = MFMA(al, bh, acc[nt]);
  }
  int col0 = lane & 15;
#pragma unroll
  for (int nt = 0; nt < 4; ++nt) {
    float bv = bias[nt * 16 + col0];
#pragma unroll
    for (int r = 0; r < 4; ++r) {
      int node = n0w + quad * 4 + r;
      float v = acc[nt][r] + bv;
      size_t o = (size_t)node * 64 + nt * 16 + col0;
      h[o] = v;
      unsigned short hi, lo; split2(v, hi, lo);
      hph[o] = hi; hpl[o] = lo;
    }
  }
}

// ---------------------------------------------------------------------------
// lin = h @ W_conv^T + b  (K=64, N=64).  fp32 out only.
// ---------------------------------------------------------------------------
__global__ __launch_bounds__(256) void k_lin(const unsigned short* __restrict__ Ah,
                                             const unsigned short* __restrict__ Al,
                                             const unsigned short* __restrict__ Wh,
                                             const unsigned short* __restrict__ Wl,
                                             const float* __restrict__ bias,
                                             float* __restrict__ lin) {
  int wave = threadIdx.x >> 6, lane = threadIdx.x & 63;
  int quad = lane >> 4;
  int n0w = blockIdx.x * 64 + wave * 16;
  int rowA = n0w + (lane & 15);
  f32x4 acc[4] = {};
#pragma unroll
  for (int ks = 0; ks < 2; ++ks) {
    bf16x8 ah = *(const bf16x8*)&Ah[(size_t)rowA * 64 + ks * 32 + quad * 8];
    bf16x8 al = *(const bf16x8*)&Al[(size_t)rowA * 64 + ks * 32 + quad * 8];
#pragma unroll
    for (int nt = 0; nt < 4; ++nt) {
      bf16x8 bh = *(const bf16x8*)&Wh[((nt * 2 + ks) * 64 + lane) * 8];
      bf16x8 bl = *(const bf16x8*)&Wl[((nt * 2 + ks) * 64 + lane) * 8];
      acc[nt] = MFMA(ah, bh, acc[nt]);
      acc[nt] = MFMA(ah, bl, acc[nt]);
      acc[nt] = MFMA(al, bh, acc[nt]);
    }
  }
  int col0 = lane & 15;
#pragma unroll
  for (int nt = 0; nt < 4; ++nt) {
    float bv = bias[nt * 16 + col0];
#pragma unroll
    for (int r = 0; r < 4; ++r) {
      int node = n0w + quad * 4 + r;
      lin[(size_t)node * 64 + nt * 16 + col0] = acc[nt][r] + bv;
    }
  }
}

// ---------------------------------------------------------------------------
// Fused GRU step with LDS-staged weight fragments.
// 5 ks-chunks (3 gi + 2 gh); per chunk the block cooperatively stages
// 12 nt x 64 lane x 16B (hi+lo) = 24.6 KB, then all 4 waves ds_read.
// gh r/z accumulate into acc[0..7]; gh n-gate kept separate in accN2.
// ---------------------------------------------------------------------------
__global__ __launch_bounds__(256) void k_gru(const unsigned short* __restrict__ Aih,
                                             const unsigned short* __restrict__ Ail,
                                             const unsigned short* __restrict__ Hh,
                                             const unsigned short* __restrict__ Hl,
                                             const unsigned short* __restrict__ Wih_h,
                                             const unsigned short* __restrict__ Wih_l,
                                             const unsigned short* __restrict__ Whh_h,
                                             const unsigned short* __restrict__ Whh_l,
                                             const float* __restrict__ b_ih,
                                             const float* __restrict__ b_hh,
                                             const float* __restrict__ h_old,
                                             float* __restrict__ h_new,
                                             unsigned short* __restrict__ hph,
                                             unsigned short* __restrict__ hpl) {
  __shared__ unsigned short sW[12288];  // hi[12][64][8] | lo[12][64][8]
  int tid = threadIdx.x;
  int wave = tid >> 6, lane = tid & 63;
  int quad = lane >> 4;
  int n0w = blockIdx.x * 64 + wave * 16;
  int rowA = n0w + (lane & 15);
  f32x4 acc[12] = {};   // gi r,z,n; gh r,z folded into [0..7]
  f32x4 accN2[4] = {};  // gh n-gate

  // ---- gi: K = 96, 3 chunks ----
  for (int ks = 0; ks < 3; ++ks) {
    __syncthreads();
    for (int i = tid; i < 768; i += 256) {
      int nt = i >> 6, r = i & 63;
      *(bf16x8*)&sW[i * 8] = *(const bf16x8*)&Wih_h[((nt * 3 + ks) * 64 + r) * 8];
      *(bf16x8*)&sW[6144 + i * 8] = *(const bf16x8*)&Wih_l[((nt * 3 + ks) * 64 + r) * 8];
    }
    __syncthreads();
    bf16x8 ah = *(const bf16x8*)&Aih[(size_t)rowA * 96 + ks * 32 + quad * 8];
    bf16x8 al = *(const bf16x8*)&Ail[(size_t)rowA * 96 + ks * 32 + quad * 8];
#pragma unroll
    for (int nt = 0; nt < 12; ++nt) {
      bf16x8 bh = *(const bf16x8*)&sW[(nt * 64 + lane) * 8];
      bf16x8 bl = *(const bf16x8*)&sW[6144 + (nt * 64 + lane) * 8];
      acc[nt] = MFMA(ah, bh, acc[nt]);
      acc[nt] = MFMA(ah, bl, acc[nt]);
      acc[nt] = MFMA(al, bh, acc[nt]);
    }
  }
  // ---- gh: K = 64, 2 chunks ----
  for (int ks = 0; ks < 2; ++ks) {
    __syncthreads();
    for (int i = tid; i < 768; i += 256) {
      int nt = i >> 6, r = i & 63;
      *(bf16x8*)&sW[i * 8] = *(const bf16x8*)&Whh_h[((nt * 2 + ks) * 64 + r) * 8];
      *(bf16x8*)&sW[6144 + i * 8] = *(const bf16x8*)&Whh_l[((nt * 2 + ks) * 64 + r) * 8];
    }
    __syncthreads();
    bf16x8 ah = *(const bf16x8*)&Hh[(size_t)rowA * 64 + ks * 32 + quad * 8];
    bf16x8 al = *(const bf16x8*)&Hl[(size_t)rowA * 64 + ks * 32 + quad * 8];
#pragma unroll
    for (int nt = 0; nt < 12; ++nt) {
      bf16x8 bh = *(const bf16x8*)&sW[(nt * 64 + lane) * 8];
      bf16x8 bl = *(const bf16x8*)&sW[6144 + (nt * 64 + lane) * 8];
      if (nt < 8) {
        acc[nt] = MFMA(ah, bh, acc[nt]);
        acc[nt] = MFMA(ah, bl, acc[nt]);
        acc[nt] = MFMA(al, bh, acc[nt]);
      } else {
        accN2[nt - 8] = MFMA(ah, bh, accN2[nt - 8]);
        accN2[nt - 8] = MFMA(ah, bl, accN2[nt - 8]);
        accN2[nt - 8] = MFMA(al, bh, accN2[nt - 8]);
      }
    }
  }

  int col0 = lane & 15;
#pragma unroll
  for (int nt = 0; nt < 4; ++nt) {
    float br  = b_ih[nt * 16 + col0]       + b_hh[nt * 16 + col0];
    float bz  = b_ih[64 + nt * 16 + col0]  + b_hh[64 + nt * 16 + col0];
    float bin = b_ih[128 + nt * 16 + col0];
    float bhn = b_hh[128 + nt * 16 + col0];
#pragma unroll
    for (int r = 0; r < 4; ++r) {
      int node = n0w + quad * 4 + r;
      size_t o = (size_t)node * 64 + nt * 16 + col0;
      float rr = sigf(acc[nt][r] + br);
      float zz = sigf(acc[nt + 4][r] + bz);
      float nn = tanhf(acc[nt + 8][r] + bin + rr * (accN2[nt][r] + bhn));
      float hv = (1.f - zz) * nn + zz * h_old[o];
      h_new[o] = hv;
      unsigned short hi, lo; split2(hv, hi, lo);
      hph[o] = hi; hpl[o] = lo;
    }
  }
}

// ---------------------------------------------------------------------------
// CSR build: histogram over dst, 1-block scan, XCD-range-partitioned placement
// ---------------------------------------------------------------------------
__global__ void k_hist(const int* __restrict__ eidx, int* __restrict__ count) {
  int t = blockIdx.x * 256 + threadIdx.x;
  if (t < Ne) atomicAdd(&count[eidx[Ne + t]], 1);
}

__global__ __launch_bounds__(1024) void k_scan(const int* __restrict__ count,
                                               int* __restrict__ rp,
                                               int* __restrict__ cursor) {
  __shared__ int sh[1024];
  int t = threadIdx.x;
  int base = t * 64;
  int sum = 0;
  for (int i = 0; i < 64; ++i) sum += count[base + i];
  sh[t] = sum;
  __syncthreads();
  for (int off = 1; off < 1024; off <<= 1) {
    int v = (t >= off) ? sh[t - off] : 0;
    __syncthreads();
    sh[t] += v;
    __syncthreads();
  }
  int run = (t == 0) ? 0 : sh[t - 1];
  for (int i = 0; i < 64; ++i) {
    int c = count[base + i];
    rp[base + i] = run;
    cursor[base + i] = run;
    run += c;
  }
  if (t == 1023) rp[Nn] = run;
}

// range = blockIdx & 7 (XCD round-robin heuristic): all writes to a given
// srcs region come from one XCD -> full-line L2 coalescing before writeback.
__global__ void k_place(const int* __restrict__ eidx, int* __restrict__ cursor,
                        int* __restrict__ srcs) {
  int range = blockIdx.x & 7;
  int chunk = blockIdx.x >> 3;
  int t0 = chunk * 4096 + threadIdx.x;
#pragma unroll
  for (int i = 0; i < 16; ++i) {
    int t = t0 + i * 256;
    int d = eidx[Ne + t];
    if ((d >> 13) == range) {
      int p = atomicAdd(&cursor[d], 1);
      srcs[p] = eidx[t];
    }
  }
}

__global__ void k_graphptr(const int* __restrict__ batch, int* __restrict__ gp) {
  int g = threadIdx.x;
  if (g > Bg) return;
  int lo = 0, hi = Nn;
  while (lo < hi) {
    int mid = (lo + hi) >> 1;
    if (batch[mid] < g) lo = mid + 1; else hi = mid;
  }
  gp[g] = lo;
}

// ---------------------------------------------------------------------------
// transpose small weights once per launch (LSTM + W1)
// ---------------------------------------------------------------------------
__global__ void k_transpose(const float* __restrict__ W_ih,
                            const float* __restrict__ W_hh,
                            const float* __restrict__ W1,
                            float* __restrict__ WihT,   // [128][256]
                            float* __restrict__ WhhT,   // [64][256]
                            float* __restrict__ W1T) {  // [128][64]
  int idx = blockIdx.x * 256 + threadIdx.x;
  if (idx < 32768) {
    int row = idx / 128, k = idx % 128;
    WihT[k * 256 + row] = W_ih[idx];
  } else if (idx < 49152) {
    int j = idx - 32768;
    int row = j / 64, k = j % 64;
    WhhT[k * 256 + row] = W_hh[j];
  } else if (idx < 57344) {
    int j = idx - 49152;
    int row = j / 128, k = j % 128;
    W1T[k * 64 + row] = W1[j];
  }
}

// ---------------------------------------------------------------------------
// CSR aggregate: m[n] = sum over in-edges of lin[src]; writes split planes.
// ---------------------------------------------------------------------------
__global__ void k_aggregate(const int* __restrict__ rp, const int* __restrict__ srcs,
                            const float* __restrict__ lin,
                            unsigned short* __restrict__ Aih,
                            unsigned short* __restrict__ Ail) {
  int t = blockIdx.x * 256 + threadIdx.x;
  int n = t >> 4;
  int q = t & 15;
  int s = rp[n], e = rp[n + 1];
  float4 acc = {0.f, 0.f, 0.f, 0.f};
  for (int i = s; i < e; ++i) {
    int src = srcs[i];
    float4 v = *(const float4*)&lin[(size_t)src * 64 + q * 4];
    acc.x += v.x; acc.y += v.y; acc.z += v.z; acc.w += v.w;
  }
  ushort4 h4, l4;
  split2(acc.x, h4.x, l4.x);
  split2(acc.y, h4.y, l4.y);
  split2(acc.z, h4.z, l4.z);
  split2(acc.w, h4.w, l4.w);
  *(ushort4*)&Aih[(size_t)n * 96 + q * 4] = h4;
  *(ushort4*)&Ail[(size_t)n * 96 + q * 4] = l4;
}

// ---------------------------------------------------------------------------
// Set2Set phase 1: LSTM cell.
// ---------------------------------------------------------------------------
__global__ __launch_bounds__(256) void k_lstm(float* __restrict__ q_star,
                                              float* __restrict__ hl,
                                              float* __restrict__ cl,
                                              const float* __restrict__ WihT,
                                              const float* __restrict__ WhhT,
                                              const float* __restrict__ b_ih,
                                              const float* __restrict__ b_hh) {
  int g = blockIdx.x, t = threadIdx.x;
  __shared__ float qs[128], hsh[64], gates[256];
  if (t < 128) qs[t] = q_star[g * 128 + t];
  else if (t < 192) hsh[t - 128] = hl[g * 64 + (t - 128)];
  __syncthreads();
  float acc = b_ih[t] + b_hh[t];
  for (int k = 0; k < 128; ++k) acc = fmaf(WihT[k * 256 + t], qs[k], acc);
  for (int k = 0; k < 64; ++k)  acc = fmaf(WhhT[k * 256 + t], hsh[k], acc);
  gates[t] = acc;
  __syncthreads();
  if (t < 64) {
    float ig = sigf(gates[t]),        fg = sigf(gates[64 + t]);
    float gg = tanhf(gates[128 + t]), og = sigf(gates[192 + t]);
    float c = fg * cl[g * 64 + t] + ig * gg;
    float q = og * tanhf(c);
    cl[g * 64 + t] = c;
    hl[g * 64 + t] = q;
    q_star[g * 128 + t] = q;
  }
}

// ---------------------------------------------------------------------------
// Set2Set phase 2: e[n] = out[n] . q[batch[n]], no atomics
// ---------------------------------------------------------------------------
__global__ __launch_bounds__(256) void k_dot(const float* __restrict__ out,
                                             const float* __restrict__ q_star,
                                             const int* __restrict__ batch,
                                             float* __restrict__ e_buf) {
  int t = blockIdx.x * 256 + threadIdx.x;
  int n = t >> 4, q16 = t & 15;
  int g = batch[n];
  float4 o  = *(const float4*)&out[(size_t)n * 64 + q16 * 4];
  float4 qv = *(const float4*)&q_star[g * 128 + q16 * 4];
  float p = o.x * qv.x + o.y * qv.y + o.z * qv.z + o.w * qv.w;
  p += __shfl_xor(p, 1); p += __shfl_xor(p, 2);
  p += __shfl_xor(p, 4); p += __shfl_xor(p, 8);
  if (q16 == 0) e_buf[n] = p;
}

// ---------------------------------------------------------------------------
// Set2Set phase 3: per-graph segment max + softmax-weighted feature sum
// ---------------------------------------------------------------------------
__global__ __launch_bounds__(256) void k_wsum(const float* __restrict__ out,
                                              const float* __restrict__ e_buf,
                                              const int* __restrict__ gp,
                                              float* __restrict__ q_star) {
  int g = blockIdx.x;
  int t = threadIdx.x;
  int w = t >> 6, lane = t & 63;
  __shared__ float wmax[4];
  __shared__ float partial[4][64];
  __shared__ float asum_p[4];
  __shared__ float emax_sh;
  int s = gp[g], e = gp[g + 1];

  float m = -INFINITY;
  for (int i = s + t; i < e; i += 256) m = fmaxf(m, e_buf[i]);
#pragma unroll
  for (int o = 32; o >= 1; o >>= 1) m = fmaxf(m, __shfl_xor(m, o));
  if (lane == 0) wmax[w] = m;
  __syncthreads();
  if (t == 0) {
    float mm = fmaxf(fmaxf(wmax[0], wmax[1]), fmaxf(wmax[2], wmax[3]));
    emax_sh = isfinite(mm) ? mm : 0.f;
  }
  __syncthreads();
  float emax = emax_sh;

  float acc = 0.f, asum = 0.f;
  for (int i = s + w; i < e; i += 4) {
    float a = expf(e_buf[i] - emax);
    asum += a;
    acc = fmaf(a, out[(size_t)i * 64 + lane], acc);
  }
  partial[w][lane] = acc;
  if (lane == 0) asum_p[w] = asum;
  __syncthreads();
  if (t < 64) {
    float r  = partial[0][t] + partial[1][t] + partial[2][t] + partial[3][t];
    float as = asum_p[0] + asum_p[1] + asum_p[2] + asum_p[3];
    q_star[g * 128 + 64 + t] = (e > s) ? r / fmaxf(as, 1e-16f) : 0.f;
  }
}

// ---------------------------------------------------------------------------
// Head
// ---------------------------------------------------------------------------
__global__ __launch_bounds__(64) void k_head(const float* __restrict__ q_star,
                                             const float* __restrict__ W1T,
                                             const float* __restrict__ b1,
                                             const float* __restrict__ W2,
                                             const float* __restrict__ b2,
                                             float* __restrict__ outp) {
  int g = blockIdx.x;
  int lane = threadIdx.x;
  __shared__ float qsh[128];
  __shared__ float hsh[64];
  __shared__ float l4[4];
  qsh[lane] = q_star[g * 128 + lane];
  qsh[64 + lane] = q_star[g * 128 + 64 + lane];
  __syncthreads();
  float acc = b1[lane];
  for (int k = 0; k < 128; ++k) acc = fmaf(W1T[k * 64 + lane], qsh[k], acc);
  hsh[lane] = fmaxf(acc, 0.f);
  __syncthreads();
  if (lane < 4) {
    float lg = b2[lane];
    for (int d = 0; d < 64; ++d) lg = fmaf(W2[lane * 64 + d], hsh[d], lg);
    l4[lane] = lg;
  }
  __syncthreads();
  if (lane < 4) {
    float m = fmaxf(fmaxf(l4[0], l4[1]), fmaxf(l4[2], l4[3]));
    float ssum = expf(l4[0] - m) + expf(l4[1] - m) + expf(l4[2] - m) + expf(l4[3] - m);
    outp[g * 4 + lane] = l4[lane] - m - logf(ssum);
  }
}

// ---------------------------------------------------------------------------
extern "C" void kernel_launch(void* const* d_in, const int* in_sizes, int n_in,
                              void* d_out, int out_size, void* d_ws, size_t ws_size,
                              hipStream_t stream) {
  const float* x        = (const float*)d_in[0];
  const int*   eidx     = (const int*)d_in[1];
  const int*   batch    = (const int*)d_in[2];
  const float* W_mlp    = (const float*)d_in[3];
  const float* b_mlp    = (const float*)d_in[4];
  const float* W_conv   = (const float*)d_in[5];
  const float* b_conv   = (const float*)d_in[6];
  const float* gW_ih    = (const float*)d_in[7];
  const float* gW_hh    = (const float*)d_in[8];
  const float* gb_ih    = (const float*)d_in[9];
  const float* gb_hh    = (const float*)d_in[10];
  const float* lW_ih    = (const float*)d_in[11];
  const float* lW_hh    = (const float*)d_in[12];
  const float* lb_ih    = (const float*)d_in[13];
  const float* lb_hh    = (const float*)d_in[14];
  const float* W1       = (const float*)d_in[15];
  const float* b1       = (const float*)d_in[16];
  const float* W2       = (const float*)d_in[17];
  const float* b2       = (const float*)d_in[18];
  float* outp = (float*)d_out;

  // ---- workspace layout ----
  char* ws = (char*)d_ws;
  size_t off = 0;
  auto alloc = [&](size_t bytes) { size_t r = off; off = (off + bytes + 255) & ~(size_t)255; return r; };
  float* hA  = (float*)(ws + alloc((size_t)Nn * 64 * 4));
  float* hB  = (float*)(ws + alloc((size_t)Nn * 64 * 4));
  unsigned short* hpAh = (unsigned short*)(ws + alloc((size_t)Nn * 64 * 2));
  unsigned short* hpAl = (unsigned short*)(ws + alloc((size_t)Nn * 64 * 2));
  unsigned short* hpBh = (unsigned short*)(ws + alloc((size_t)Nn * 64 * 2));
  unsigned short* hpBl = (unsigned short*)(ws + alloc((size_t)Nn * 64 * 2));
  unsigned short* Axh  = (unsigned short*)(ws + alloc((size_t)Nn * 32 * 2));
  unsigned short* Axl  = (unsigned short*)(ws + alloc((size_t)Nn * 32 * 2));
  unsigned short* Aih  = (unsigned short*)(ws + alloc((size_t)Nn * 96 * 2));
  unsigned short* Ail  = (unsigned short*)(ws + alloc((size_t)Nn * 96 * 2));
  float* lin   = (float*)(ws + alloc((size_t)Nn * 64 * 4));
  int*   count = (int*)(ws + alloc((size_t)Nn * 4));
  int*   rp    = (int*)(ws + alloc((size_t)(Nn + 1) * 4));
  int*   cursor= (int*)(ws + alloc((size_t)Nn * 4));
  int*   srcs  = (int*)(ws + alloc((size_t)Ne * 4));
  int*   gp    = (int*)(ws + alloc((size_t)(Bg + 1) * 4));
  float* e_buf = (float*)(ws + alloc((size_t)Nn * 4));
  float* WihT  = (float*)(ws + alloc((size_t)128 * 256 * 4));
  float* WhhT  = (float*)(ws + alloc((size_t)64 * 256 * 4));
  float* W1T   = (float*)(ws + alloc((size_t)128 * 64 * 4));
  unsigned short* mlp_h = (unsigned short*)(ws + alloc(2048 * 2));
  unsigned short* mlp_l = (unsigned short*)(ws + alloc(2048 * 2));
  unsigned short* cv_h  = (unsigned short*)(ws + alloc(4096 * 2));
  unsigned short* cv_l  = (unsigned short*)(ws + alloc(4096 * 2));
  unsigned short* ih_h  = (unsigned short*)(ws + alloc(18432 * 2));
  unsigned short* ih_l  = (unsigned short*)(ws + alloc(18432 * 2));
  unsigned short* hh_h  = (unsigned short*)(ws + alloc(12288 * 2));
  unsigned short* hh_l  = (unsigned short*)(ws + alloc(12288 * 2));
  float* s2s   = (float*)(ws + alloc((size_t)Bg * (128 + 64 + 64) * 4));
  float* q_star = s2s;
  float* hl     = s2s + Bg * 128;
  float* cl     = s2s + Bg * 128 + Bg * 64;
  (void)in_sizes; (void)n_in; (void)out_size; (void)ws_size;

  hipMemsetAsync(count, 0, (size_t)Nn * 4, stream);
  hipMemsetAsync(s2s, 0, (size_t)Bg * 256 * 4, stream);

  // CSR build + small packs
  k_hist<<<Ne / 256, 256, 0, stream>>>(eidx, count);
  k_scan<<<1, 1024, 0, stream>>>(count, rp, cursor);
  k_place<<<2048, 256, 0, stream>>>(eidx, cursor, srcs);
  k_graphptr<<<1, 512, 0, stream>>>(batch, gp);
  k_transpose<<<224, 256, 0, stream>>>(lW_ih, lW_hh, W1, WihT, WhhT, W1T);
  k_packw<<<144, 256, 0, stream>>>(W_mlp, W_conv, gW_ih, gW_hh,
                                   mlp_h, mlp_l, cv_h, cv_l, ih_h, ih_l, hh_h, hh_l);
  k_prepx<<<Nn * DIN / 256, 256, 0, stream>>>(x, Axh, Axl, Aih, Ail);

  // conv1
  k_conv1<<<Nn / 64, 256, 0, stream>>>(Axh, Axl, mlp_h, mlp_l, b_mlp, hA, hpAh, hpAl);

  float* h = hA; float* h2 = hB;
  unsigned short *cph = hpAh, *cpl = hpAl, *nph = hpBh, *npl = hpBl;
  for (int step = 0; step < 2; ++step) {
    k_lin<<<Nn / 64, 256, 0, stream>>>(cph, cpl, cv_h, cv_l, b_conv, lin);
    k_aggregate<<<Nn * 16 / 256, 256, 0, stream>>>(rp, srcs, lin, Aih, Ail);
    k_gru<<<Nn / 64, 256, 0, stream>>>(Aih, Ail, cph, cpl, ih_h, ih_l, hh_h, hh_l,
                                       gb_ih, gb_hh, h, h2, nph, npl);
    float* tf = h; h = h2; h2 = tf;
    unsigned short* tu;
    tu = cph; cph = nph; nph = tu;
    tu = cpl; cpl = npl; npl = tu;
  }

  for (int it = 0; it < 3; ++it) {
    k_lstm<<<Bg, 256, 0, stream>>>(q_star, hl, cl, WihT, WhhT, lb_ih, lb_hh);
    k_dot<<<Nn * 16 / 256, 256, 0, stream>>>(h, q_star, batch, e_buf);
    k_wsum<<<Bg, 256, 0, stream>>>(h, e_buf, gp, q_star);
  }
  k_head<<<Bg, 64, 0, stream>>>(q_star, W1T, b1, W2, b2, outp);
}